// Round 1
// baseline (538.956 us; speedup 1.0000x reference)
//
#include <hip/hip_runtime.h>
#include <math.h>

#define DEV __device__ __forceinline__

typedef __attribute__((ext_vector_type(8))) short short8;
typedef __attribute__((ext_vector_type(4))) short short4v;
typedef __attribute__((ext_vector_type(2))) short short2v;
typedef __attribute__((ext_vector_type(4))) float f32x4;

DEV short f2bf(float f) {
    unsigned u = __builtin_bit_cast(unsigned, f);
    unsigned r = (u + 0x7fffu + ((u >> 16) & 1u)) >> 16;
    return (short)r;
}
DEV float b2f(short s) {
    unsigned u = ((unsigned)(unsigned short)s) << 16;
    return __builtin_bit_cast(float, u);
}

// ---------------------------------------------------------------------------
// Pack conv weights into MFMA A-fragment order.
// dst[((ks*7+mt)*64+lane)*8 + j] = W[f=mt*16+(lane&15)][kappa=ks*32+(lane>>4)*8+j]
// mode 0: 3-tap conv, w [100][100][3], kappa = dk*112 + c  (K = 336, padded 352)
// mode 1: conv3 loc-half, w [100][200], kappa = c (use cols 100..199), K pad 128
// ---------------------------------------------------------------------------
__global__ __launch_bounds__(64) void pack_A_kernel(const float* __restrict__ w,
                                                    short* __restrict__ dst, int mode) {
    int bx = blockIdx.x;
    int ks = bx / 7, mt = bx - ks * 7;
    int lane = threadIdx.x;
    int f = mt * 16 + (lane & 15);
    int kb = ks * 32 + (lane >> 4) * 8;
    short8 v;
#pragma unroll
    for (int j = 0; j < 8; ++j) {
        int kk = kb + j;
        float val = 0.f;
        if (f < 100) {
            if (mode == 0) {
                int dk = kk / 112, c = kk - dk * 112;
                if (dk < 3 && c < 100) val = w[(f * 100 + c) * 3 + dk];
            } else {
                if (kk < 100) val = w[f * 200 + 100 + kk];
            }
        }
        v[j] = f2bf(val);
    }
    *(short8*)&dst[(bx * 64 + lane) * 8] = v;
}

// ---------------------------------------------------------------------------
// MFMA conv kernel. C-tile per block: M=112 (f, 7 mt) x N=128 (l, 8 nt).
// 4 waves; wave w owns nt = {2w, 2w+1}; per ks: 7 A-frags + 2 B-frags, 14 MFMA.
// TAPS==3: s_in[130][112], row j <-> l = l0-1+j (halo, zero padded).
// TAPS==1: s_in[128][128], row j <-> l = l0+j, cols >=112 zero.
// FUSED: epilogue computes relu(acc+zg)*w4, reduces over f -> logits[b][l].
// ---------------------------------------------------------------------------
template<int TAPS, int NKS, bool GATHER, bool FUSED>
__global__ __launch_bounds__(256) void conv_mfma_kernel(
    const short* __restrict__ inT, const float* __restrict__ emb,
    const int* __restrict__ xidx, const short* __restrict__ Apack,
    const float* __restrict__ bias, const float* __restrict__ zg,
    const float* __restrict__ w4, const float* __restrict__ b4,
    short* __restrict__ outT, float* __restrict__ logits) {
    constexpr int SINC = (TAPS == 3) ? 112 : 128;
    constexpr int NROW = (TAPS == 3) ? 130 : 128;
    extern __shared__ char smem[];
    short* s_in = (short*)smem;
    short* s_A  = (short*)(smem + NROW * SINC * 2);

    const int tid = threadIdx.x;
    const int b = blockIdx.y;
    const int l0 = blockIdx.x * 128;
    const int lane = tid & 63, wv = tid >> 6;
    const int q = lane >> 4, n = lane & 15;

    // ---- stage input tile into LDS (bf16) ----
    if constexpr (GATHER) {
        int c2 = tid & 63;   // column pair index (c = 2*c2, 2*c2+1)
        int jj = tid >> 6;   // 4 rows per pass
        for (int p = 0; p < 33; ++p) {
            int j = p * 4 + jj;
            if (j < 130 && c2 < 56) {
                int lg = l0 - 1 + j;
                short2v v; v[0] = 0; v[1] = 0;
                if (lg >= 0 && lg < 512) {
                    int row = xidx[b * 512 + lg];
                    int c = c2 * 2;
                    if (c < 100) {
                        const float* ep = &emb[row * 100 + c];
                        v[0] = f2bf(ep[0]);
                        v[1] = (c + 1 < 100) ? f2bf(ep[1]) : (short)0;
                    }
                }
                *(short2v*)&s_in[j * 112 + c2 * 2] = v;
            }
        }
    } else if constexpr (TAPS == 3) {
        for (int idx = tid; idx < 130 * 14; idx += 256) {
            int j = idx / 14, cc = idx - j * 14;
            int lg = l0 - 1 + j;
            short8 v;
#pragma unroll
            for (int z = 0; z < 8; ++z) v[z] = 0;
            if (lg >= 0 && lg < 512)
                v = *(const short8*)&inT[(b * 512 + lg) * 112 + cc * 8];
            *(short8*)&s_in[j * 112 + cc * 8] = v;
        }
    } else {
        for (int idx = tid; idx < 128 * 16; idx += 256) {
            int j = idx >> 4, cc = idx & 15;
            short8 v;
#pragma unroll
            for (int z = 0; z < 8; ++z) v[z] = 0;
            if (cc < 14)
                v = *(const short8*)&inT[(b * 512 + l0 + j) * 112 + cc * 8];
            *(short8*)&s_in[j * 128 + cc * 8] = v;
        }
    }

    const f32x4 z4 = {0.f, 0.f, 0.f, 0.f};
    f32x4 acc[7][2];
#pragma unroll
    for (int mt = 0; mt < 7; ++mt) { acc[mt][0] = z4; acc[mt][1] = z4; }

    for (int ks = 0; ks < NKS; ++ks) {
        __syncthreads();
        for (int idx = tid; idx < 448; idx += 256)
            *(short8*)&s_A[idx * 8] = *(const short8*)&Apack[(ks * 448 + idx) * 8];
        __syncthreads();

        int oct = ks * 4 + q;
        int dk, c0;
        if (TAPS == 3) {
            if (oct >= 42) { dk = 0; c0 = 0; }   // zero-padded kappa; A is 0 there
            else { dk = oct / 14; c0 = (oct - dk * 14) * 8; }
        } else { dk = 0; c0 = oct * 8; }

        short8 bfr[2];
#pragma unroll
        for (int t = 0; t < 2; ++t) {
            int j = (wv * 2 + t) * 16 + n + dk;
            bfr[t] = *(const short8*)&s_in[j * SINC + c0];
        }
#pragma unroll
        for (int mt = 0; mt < 7; ++mt) {
            short8 af = *(const short8*)&s_A[(mt * 64 + lane) * 8];
            acc[mt][0] = __builtin_amdgcn_mfma_f32_16x16x32_bf16(af, bfr[0], acc[mt][0], 0, 0, 0);
            acc[mt][1] = __builtin_amdgcn_mfma_f32_16x16x32_bf16(af, bfr[1], acc[mt][1], 0, 0, 0);
        }
    }

    if constexpr (!FUSED) {
#pragma unroll
        for (int mt = 0; mt < 7; ++mt) {
            int fb = mt * 16 + q * 4;
            f32x4 bs = (fb < 100) ? *(const f32x4*)&bias[fb] : z4;
#pragma unroll
            for (int t = 0; t < 2; ++t) {
                int l = l0 + (wv * 2 + t) * 16 + n;
                short4v pk;
#pragma unroll
                for (int r = 0; r < 4; ++r)
                    pk[r] = f2bf(fmaxf(acc[mt][t][r] + bs[r], 0.f));
                *(short4v*)&outT[(b * 512 + l) * 112 + fb] = pk;
            }
        }
    } else {
        f32x4 w4v[7], zgv[7];
#pragma unroll
        for (int mt = 0; mt < 7; ++mt) {
            int fb = mt * 16 + q * 4;
            w4v[mt] = (fb < 100) ? *(const f32x4*)&w4[fb] : z4;
            zgv[mt] = *(const f32x4*)&zg[b * 112 + fb];   // zg padded with zeros
        }
#pragma unroll
        for (int t = 0; t < 2; ++t) {
            float part = 0.f;
#pragma unroll
            for (int mt = 0; mt < 7; ++mt)
#pragma unroll
                for (int r = 0; r < 4; ++r) {
                    float zv = fmaxf(acc[mt][t][r] + zgv[mt][r], 0.f);
                    part += zv * w4v[mt][r];
                }
            part += __shfl_xor(part, 16, 64);
            part += __shfl_xor(part, 32, 64);
            if (q == 0) {
                int l = l0 + (wv * 2 + t) * 16 + n;
                logits[b * 512 + l] = part + b4[0];
            }
        }
    }
}

// ---------------------------------------------------------------------------
// Pool h over L, gate MLP, and fold g through conv3's g-half into zg[b,f]
// zg[b,f] = conv3_b[f] + sum_h g[b,h] * w3[f][h]   (f>=100 -> 0)
// ---------------------------------------------------------------------------
__global__ __launch_bounds__(256) void pool_gate_kernel(
    const short* __restrict__ hT, const float* __restrict__ gi_w,
    const float* __restrict__ gi_b, const float* __restrict__ w3,
    const float* __restrict__ b3, float* __restrict__ zg) {
    int b = blockIdx.x, tid = threadIdx.x;
    __shared__ float s_part[2][112];
    __shared__ float s_hm[112];
    __shared__ float s_g[100];
    int c = tid & 127, lq = tid >> 7;
    if (c < 112) {
        float a = 0.f;
        for (int l = lq; l < 512; l += 2) a += b2f(hT[(b * 512 + l) * 112 + c]);
        s_part[lq][c] = a;
    }
    __syncthreads();
    if (tid < 112) s_hm[tid] = (s_part[0][tid] + s_part[1][tid]) * (1.f / 512.f);
    __syncthreads();
    if (tid < 100) {
        float a = gi_b[tid];
        for (int f = 0; f < 100; ++f) a += s_hm[f] * gi_w[tid * 100 + f];
        s_g[tid] = fmaxf(a, 0.f);
    }
    __syncthreads();
    if (tid < 112) {
        float a = 0.f;
        if (tid < 100) {
            a = b3[tid];
            for (int h = 0; h < 100; ++h) a += s_g[h] * w3[tid * 200 + h];
        }
        zg[b * 112 + tid] = a;
    }
}

// ---------------------------------------------------------------------------
// Gumbel top-k continuous sampler: csamples[b,l] = max_k softmax_l((gum+logit)/T)
// ---------------------------------------------------------------------------
__global__ __launch_bounds__(256) void sampler_kernel(
    const float* __restrict__ u, const float* __restrict__ logits,
    float* __restrict__ cs) {
    const float EPSV = 1.1920929e-07f;
    int b = blockIdx.x, tid = threadIdx.x;
    int lane = tid & 63, wv = tid >> 6;
    __shared__ float s_log[512], s_cs[512], s_red[8];
    for (int l = tid; l < 512; l += 256) { s_log[l] = logits[b * 512 + l]; s_cs[l] = 0.f; }
    __syncthreads();
    for (int k = 0; k < 10; ++k) {
        float nz[2];
#pragma unroll
        for (int i = 0; i < 2; ++i) {
            int l = tid + i * 256;
            float uu = u[(b * 10 + k) * 512 + l];
            uu = fminf(fmaxf(uu, EPSV), 1.f - EPSV);
            float g = -logf(-logf(uu));
            nz[i] = (g + s_log[l]) * (1.f / 0.3f);
        }
        float m = fmaxf(nz[0], nz[1]);
#pragma unroll
        for (int off = 32; off >= 1; off >>= 1) m = fmaxf(m, __shfl_xor(m, off, 64));
        if (lane == 0) s_red[wv] = m;
        __syncthreads();
        m = fmaxf(fmaxf(s_red[0], s_red[1]), fmaxf(s_red[2], s_red[3]));
        float e0 = expf(nz[0] - m), e1 = expf(nz[1] - m);
        float s = e0 + e1;
#pragma unroll
        for (int off = 32; off >= 1; off >>= 1) s += __shfl_xor(s, off, 64);
        if (lane == 0) s_red[4 + wv] = s;
        __syncthreads();
        float inv = 1.f / (s_red[4] + s_red[5] + s_red[6] + s_red[7]);
        s_cs[tid]       = fmaxf(s_cs[tid],       e0 * inv);
        s_cs[tid + 256] = fmaxf(s_cs[tid + 256], e1 * inv);
    }
    for (int l = tid; l < 512; l += 256) cs[b * 512 + l] = s_cs[l];
}

// ---------------------------------------------------------------------------
// Distil head: pooled = mean_l emb[x]*cs ; h2 = relu(fc1) ; out = sigmoid(head)
// ---------------------------------------------------------------------------
__global__ __launch_bounds__(256) void head_kernel(
    const int* __restrict__ xidx, const float* __restrict__ emb,
    const float* __restrict__ cs, const float* __restrict__ fc1_w,
    const float* __restrict__ fc1_b, const float* __restrict__ head_w,
    const float* __restrict__ head_b, float* __restrict__ out) {
    int b = blockIdx.x, tid = threadIdx.x;
    int lane = tid & 63, wv = tid >> 6;
    __shared__ float s_part[2][100];
    __shared__ float s_pool[100];
    __shared__ float s_h2[100];
    __shared__ float s_red[4];
    int e = tid & 127, lq = tid >> 7;
    float a = 0.f;
    for (int l = lq; l < 512; l += 2) {
        int row = xidx[b * 512 + l];
        float cv = cs[b * 512 + l];
        if (e < 100) a += emb[row * 100 + e] * cv;
    }
    if (e < 100) s_part[lq][e] = a;
    __syncthreads();
    if (tid < 100) s_pool[tid] = (s_part[0][tid] + s_part[1][tid]) * (1.f / 512.f);
    __syncthreads();
    if (tid < 100) {
        float acc = fc1_b[tid];
        for (int i = 0; i < 100; ++i) acc += s_pool[i] * fc1_w[tid * 100 + i];
        s_h2[tid] = fmaxf(acc, 0.f);
    }
    __syncthreads();
    float v = (tid < 100) ? s_h2[tid] * head_w[tid] : 0.f;
#pragma unroll
    for (int off = 32; off >= 1; off >>= 1) v += __shfl_xor(v, off, 64);
    if (lane == 0) s_red[wv] = v;
    __syncthreads();
    if (tid == 0) {
        float z = s_red[0] + s_red[1] + s_red[2] + s_red[3] + head_b[0];
        out[b] = 1.f / (1.f + expf(-z));
    }
}

// ---------------------------------------------------------------------------
extern "C" void kernel_launch(void* const* d_in, const int* in_sizes, int n_in,
                              void* d_out, int out_size, void* d_ws, size_t ws_size,
                              hipStream_t stream) {
    const int*   x   = (const int*)d_in[0];
    const float* u   = (const float*)d_in[1];
    const float* emb = (const float*)d_in[2];
    const float* c1w = (const float*)d_in[3];
    const float* c1b = (const float*)d_in[4];
    const float* giw = (const float*)d_in[5];
    const float* gib = (const float*)d_in[6];
    const float* c2w = (const float*)d_in[7];
    const float* c2b = (const float*)d_in[8];
    const float* liw = (const float*)d_in[9];
    const float* lib = (const float*)d_in[10];
    const float* c3w = (const float*)d_in[11];
    const float* c3b = (const float*)d_in[12];
    const float* c4w = (const float*)d_in[13];
    const float* c4b = (const float*)d_in[14];
    const float* f1w = (const float*)d_in[15];
    const float* f1b = (const float*)d_in[16];
    const float* hww = (const float*)d_in[17];
    const float* hbb = (const float*)d_in[18];
    float* out = (float*)d_out;

    char* ws = (char*)d_ws;
    short* hT     = (short*)(ws + 0);           // [512][512][112] bf16, later locT
    short* tT     = (short*)(ws + 58720256);    // [512][512][112] bf16
    short* A1     = (short*)(ws + 117440512);   // 11*448*16 B
    short* A2     = (short*)(ws + 117519360);
    short* A3     = (short*)(ws + 117598208);
    short* A4     = (short*)(ws + 117677056);   // 4*448*16 B
    float* zg     = (float*)(ws + 117705728);   // [512][112] f32
    float* logits = (float*)(ws + 117935104);   // [512][512] f32
    short* locT = hT;  // h dead after conv2; reuse

    pack_A_kernel<<<77, 64, 0, stream>>>(c1w, A1, 0);
    pack_A_kernel<<<77, 64, 0, stream>>>(c2w, A2, 0);
    pack_A_kernel<<<77, 64, 0, stream>>>(liw, A3, 0);
    pack_A_kernel<<<28, 64, 0, stream>>>(c3w, A4, 1);

    dim3 cgrid(4, 512);
    size_t smem3 = 130 * 112 * 2 + 448 * 16;  // 36288 B
    size_t smem1 = 128 * 128 * 2 + 448 * 16;  // 39936 B

    conv_mfma_kernel<3, 11, true, false><<<cgrid, 256, smem3, stream>>>(
        nullptr, emb, x, A1, c1b, nullptr, nullptr, nullptr, hT, nullptr);
    pool_gate_kernel<<<512, 256, 0, stream>>>(hT, giw, gib, c3w, c3b, zg);
    conv_mfma_kernel<3, 11, false, false><<<cgrid, 256, smem3, stream>>>(
        hT, nullptr, nullptr, A2, c2b, nullptr, nullptr, nullptr, tT, nullptr);
    conv_mfma_kernel<3, 11, false, false><<<cgrid, 256, smem3, stream>>>(
        tT, nullptr, nullptr, A3, lib, nullptr, nullptr, nullptr, locT, nullptr);
    conv_mfma_kernel<1, 4, false, true><<<cgrid, 256, smem1, stream>>>(
        locT, nullptr, nullptr, A4, nullptr, zg, c4w, c4b, nullptr, logits);
    sampler_kernel<<<512, 256, 0, stream>>>(u, logits, out + 512);
    head_kernel<<<512, 256, 0, stream>>>(x, emb, out + 512, f1w, f1b, hww, hbb, out);
}

// Round 2
// 357.845 us; speedup vs baseline: 1.5061x; 1.5061x over previous
//
#include <hip/hip_runtime.h>
#include <math.h>

#define DEV __device__ __forceinline__

typedef __attribute__((ext_vector_type(8))) short short8;
typedef __attribute__((ext_vector_type(4))) short short4v;
typedef __attribute__((ext_vector_type(2))) short short2v;
typedef __attribute__((ext_vector_type(4))) float f32x4;

DEV short f2bf(float f) {
    unsigned u = __builtin_bit_cast(unsigned, f);
    unsigned r = (u + 0x7fffu + ((u >> 16) & 1u)) >> 16;
    return (short)r;
}
DEV float b2f(short s) {
    unsigned u = ((unsigned)(unsigned short)s) << 16;
    return __builtin_bit_cast(float, u);
}

// ---------------------------------------------------------------------------
// Pack conv weights into MFMA A-fragment order.
// dst[((ks*7+mt)*64+lane)*8 + j] = W[f=mt*16+(lane&15)][kappa=ks*32+(lane>>4)*8+j]
// mode 0: 3-tap conv, w [100][100][3], kappa = dk*112 + c  (K = 336, padded 352)
// mode 1: conv3 loc-half, w [100][200], kappa = c (use cols 100..199), K pad 128
// ---------------------------------------------------------------------------
__global__ __launch_bounds__(64) void pack_A_kernel(const float* __restrict__ w,
                                                    short* __restrict__ dst, int mode) {
    int bx = blockIdx.x;
    int ks = bx / 7, mt = bx - ks * 7;
    int lane = threadIdx.x;
    int f = mt * 16 + (lane & 15);
    int kb = ks * 32 + (lane >> 4) * 8;
    short8 v;
#pragma unroll
    for (int j = 0; j < 8; ++j) {
        int kk = kb + j;
        float val = 0.f;
        if (f < 100) {
            if (mode == 0) {
                int dk = kk / 112, c = kk - dk * 112;
                if (dk < 3 && c < 100) val = w[(f * 100 + c) * 3 + dk];
            } else {
                if (kk < 100) val = w[f * 200 + 100 + kk];
            }
        }
        v[j] = f2bf(val);
    }
    *(short8*)&dst[(bx * 64 + lane) * 8] = v;
}

// ---------------------------------------------------------------------------
// MFMA conv kernel. C-tile per block: M=112 (f, 7 mt) x N=128 (l, 8 nt).
// LDS row stride 120 shorts (240 B = 60 banks -> 2-way conflict = free).
// A-fragments are loaded straight from global (coalesced, L2-resident, 77 KB)
// -> only ONE barrier per block (after input staging).
// TAPS==3: s_in[130][120], row j <-> l = l0-1+j (halo, zero padded).
// TAPS==1: s_in[128][120], row j <-> l = l0+j, cols >=100 zero.
// POOL: epilogue also reduces relu(acc+b) over l -> hpart[b][blk][112].
// FUSED: epilogue computes relu(acc+zg)*w4, reduces over f -> logits[b][l].
// ---------------------------------------------------------------------------
template<int TAPS, int NKS, bool GATHER, bool FUSED, bool POOL>
__global__ __launch_bounds__(256) void conv_mfma_kernel(
    const short* __restrict__ inT, const float* __restrict__ emb,
    const int* __restrict__ xidx, const short* __restrict__ Apack,
    const float* __restrict__ bias, const float* __restrict__ zg,
    const float* __restrict__ w4, const float* __restrict__ b4,
    short* __restrict__ outT, float* __restrict__ logits,
    float* __restrict__ hpart) {
    constexpr int SINC = 120;
    constexpr int NROW = (TAPS == 3) ? 130 : 128;
    extern __shared__ char smem[];
    short* s_in = (short*)smem;
    char*  s_ex = smem + NROW * SINC * 2;   // 1792 B: s_x during staging, s_pool in epilogue
    int*   s_x    = (int*)s_ex;
    float* s_pool = (float*)s_ex;

    const int tid = threadIdx.x;
    const int b = blockIdx.y;
    const int l0 = blockIdx.x * 128;
    const int lane = tid & 63, wv = tid >> 6;
    const int q = lane >> 4, n = lane & 15;

    // ---- stage input tile into LDS (bf16) ----
    if constexpr (GATHER) {
        for (int j = tid; j < 130; j += 256) {
            int lg = l0 - 1 + j;
            s_x[j] = (lg >= 0 && lg < 512) ? xidx[b * 512 + lg] : -1;
        }
        __syncthreads();
        int c4 = tid & 31, j0 = tid >> 5;
        for (int p = 0; p < 17; ++p) {
            int j = p * 8 + j0;
            if (j < 130) {
                if (c4 < 25) {
                    int row = s_x[j];
                    short4v v; v[0] = 0; v[1] = 0; v[2] = 0; v[3] = 0;
                    if (row >= 0) {
                        f32x4 ev = *(const f32x4*)&emb[row * 100 + c4 * 4];
#pragma unroll
                        for (int r = 0; r < 4; ++r) v[r] = f2bf(ev[r]);
                    }
                    *(short4v*)&s_in[j * 120 + c4 * 4] = v;
                } else if (c4 < 30) {
                    short4v z; z[0] = 0; z[1] = 0; z[2] = 0; z[3] = 0;
                    *(short4v*)&s_in[j * 120 + 100 + (c4 - 25) * 4] = z;
                }
            }
        }
    } else if constexpr (TAPS == 3) {
        for (int idx = tid; idx < 130 * 15; idx += 256) {
            int j = idx / 15, c8 = idx - j * 15;
            int lg = l0 - 1 + j;
            short8 v;
#pragma unroll
            for (int z = 0; z < 8; ++z) v[z] = 0;
            if (lg >= 0 && lg < 512 && c8 < 14)
                v = *(const short8*)&inT[(b * 512 + lg) * 112 + c8 * 8];
            *(short8*)&s_in[j * 120 + c8 * 8] = v;
        }
    } else {
        for (int idx = tid; idx < 128 * 15; idx += 256) {
            int j = idx / 15, c8 = idx - j * 15;
            short8 v;
#pragma unroll
            for (int z = 0; z < 8; ++z) v[z] = 0;
            if (c8 < 14)
                v = *(const short8*)&inT[(b * 512 + l0 + j) * 112 + c8 * 8];
            *(short8*)&s_in[j * 120 + c8 * 8] = v;
        }
    }
    __syncthreads();

    const f32x4 z4 = {0.f, 0.f, 0.f, 0.f};
    f32x4 acc[7][2];
#pragma unroll
    for (int mt = 0; mt < 7; ++mt) { acc[mt][0] = z4; acc[mt][1] = z4; }

    for (int ks = 0; ks < NKS; ++ks) {
        int oct = ks * 4 + q;
        int dk, c0;
        if (TAPS == 3) {
            if (oct >= 42) { dk = 0; c0 = 0; }   // zero-padded kappa; A is 0 there
            else { dk = oct / 14; c0 = (oct - dk * 14) * 8; }
        } else {
            dk = 0; c0 = oct * 8;
            if (c0 > 104) c0 = 104;              // A is 0 for kappa>=104 anyway
        }

        short8 bfr[2];
#pragma unroll
        for (int t = 0; t < 2; ++t) {
            int j = (wv * 2 + t) * 16 + n + dk;
            bfr[t] = *(const short8*)&s_in[j * 120 + c0];
        }
#pragma unroll
        for (int mt = 0; mt < 7; ++mt) {
            short8 af = *(const short8*)&Apack[(ks * 448 + mt * 64 + lane) * 8];
            acc[mt][0] = __builtin_amdgcn_mfma_f32_16x16x32_bf16(af, bfr[0], acc[mt][0], 0, 0, 0);
            acc[mt][1] = __builtin_amdgcn_mfma_f32_16x16x32_bf16(af, bfr[1], acc[mt][1], 0, 0, 0);
        }
    }

    if constexpr (!FUSED) {
        f32x4 psum[7];
#pragma unroll
        for (int mt = 0; mt < 7; ++mt) psum[mt] = z4;
#pragma unroll
        for (int mt = 0; mt < 7; ++mt) {
            int fb = mt * 16 + q * 4;
            f32x4 bs = (fb < 100) ? *(const f32x4*)&bias[fb] : z4;
#pragma unroll
            for (int t = 0; t < 2; ++t) {
                int l = l0 + (wv * 2 + t) * 16 + n;
                short4v pk;
#pragma unroll
                for (int r = 0; r < 4; ++r) {
                    float v = fmaxf(acc[mt][t][r] + bs[r], 0.f);
                    pk[r] = f2bf(v);
                    if constexpr (POOL) psum[mt][r] += v;
                }
                *(short4v*)&outT[(b * 512 + l) * 112 + fb] = pk;
            }
        }
        if constexpr (POOL) {
#pragma unroll
            for (int mt = 0; mt < 7; ++mt)
#pragma unroll
                for (int off = 1; off <= 8; off <<= 1)
#pragma unroll
                    for (int r = 0; r < 4; ++r)
                        psum[mt][r] += __shfl_xor(psum[mt][r], off, 64);
            if (n == 0) {
#pragma unroll
                for (int mt = 0; mt < 7; ++mt)
                    *(f32x4*)&s_pool[wv * 112 + mt * 16 + q * 4] = psum[mt];
            }
            __syncthreads();
            if (tid < 112) {
                float s = s_pool[tid] + s_pool[112 + tid] + s_pool[224 + tid] + s_pool[336 + tid];
                hpart[(b * 4 + blockIdx.x) * 112 + tid] = s;
            }
        }
    } else {
        f32x4 w4v[7], zgv[7];
#pragma unroll
        for (int mt = 0; mt < 7; ++mt) {
            int fb = mt * 16 + q * 4;
            w4v[mt] = (fb < 100) ? *(const f32x4*)&w4[fb] : z4;
            zgv[mt] = *(const f32x4*)&zg[b * 112 + fb];   // zg padded with zeros
        }
#pragma unroll
        for (int t = 0; t < 2; ++t) {
            float part = 0.f;
#pragma unroll
            for (int mt = 0; mt < 7; ++mt)
#pragma unroll
                for (int r = 0; r < 4; ++r) {
                    float zv = fmaxf(acc[mt][t][r] + zgv[mt][r], 0.f);
                    part += zv * w4v[mt][r];
                }
            part += __shfl_xor(part, 16, 64);
            part += __shfl_xor(part, 32, 64);
            if (q == 0) {
                int l = l0 + (wv * 2 + t) * 16 + n;
                logits[b * 512 + l] = part + b4[0];
            }
        }
    }
}

// ---------------------------------------------------------------------------
// Finish pool: hm = sum(hpart)/512, gate MLP, fold g through conv3 g-half:
// zg[b,f] = conv3_b[f] + sum_h g[b,h] * w3[f][h]   (f>=100 -> 0)
// ---------------------------------------------------------------------------
__global__ __launch_bounds__(128) void pool_gate_kernel(
    const float* __restrict__ hpart, const float* __restrict__ gi_w,
    const float* __restrict__ gi_b, const float* __restrict__ w3,
    const float* __restrict__ b3, float* __restrict__ zg) {
    int b = blockIdx.x, tid = threadIdx.x;
    __shared__ float s_hm[112];
    __shared__ float s_g[100];
    if (tid < 112) {
        float a = 0.f;
#pragma unroll
        for (int sb = 0; sb < 4; ++sb) a += hpart[(b * 4 + sb) * 112 + tid];
        s_hm[tid] = a * (1.f / 512.f);
    }
    __syncthreads();
    if (tid < 100) {
        float a = gi_b[tid];
        for (int f = 0; f < 100; ++f) a += s_hm[f] * gi_w[tid * 100 + f];
        s_g[tid] = fmaxf(a, 0.f);
    }
    __syncthreads();
    if (tid < 112) {
        float a = 0.f;
        if (tid < 100) {
            a = b3[tid];
            for (int h = 0; h < 100; ++h) a += s_g[h] * w3[tid * 200 + h];
        }
        zg[b * 112 + tid] = a;
    }
}

// ---------------------------------------------------------------------------
// Gumbel top-k continuous sampler: csamples[b,l] = max_k softmax_l((gum+logit)/T)
// ---------------------------------------------------------------------------
__global__ __launch_bounds__(256) void sampler_kernel(
    const float* __restrict__ u, const float* __restrict__ logits,
    float* __restrict__ cs) {
    const float EPSV = 1.1920929e-07f;
    int b = blockIdx.x, tid = threadIdx.x;
    int lane = tid & 63, wv = tid >> 6;
    __shared__ float s_log[512], s_cs[512], s_red[8];
    for (int l = tid; l < 512; l += 256) { s_log[l] = logits[b * 512 + l]; s_cs[l] = 0.f; }
    __syncthreads();
    for (int k = 0; k < 10; ++k) {
        float nz[2];
#pragma unroll
        for (int i = 0; i < 2; ++i) {
            int l = tid + i * 256;
            float uu = u[(b * 10 + k) * 512 + l];
            uu = fminf(fmaxf(uu, EPSV), 1.f - EPSV);
            float g = -logf(-logf(uu));
            nz[i] = (g + s_log[l]) * (1.f / 0.3f);
        }
        float m = fmaxf(nz[0], nz[1]);
#pragma unroll
        for (int off = 32; off >= 1; off >>= 1) m = fmaxf(m, __shfl_xor(m, off, 64));
        if (lane == 0) s_red[wv] = m;
        __syncthreads();
        m = fmaxf(fmaxf(s_red[0], s_red[1]), fmaxf(s_red[2], s_red[3]));
        float e0 = expf(nz[0] - m), e1 = expf(nz[1] - m);
        float s = e0 + e1;
#pragma unroll
        for (int off = 32; off >= 1; off >>= 1) s += __shfl_xor(s, off, 64);
        if (lane == 0) s_red[4 + wv] = s;
        __syncthreads();
        float inv = 1.f / (s_red[4] + s_red[5] + s_red[6] + s_red[7]);
        s_cs[tid]       = fmaxf(s_cs[tid],       e0 * inv);
        s_cs[tid + 256] = fmaxf(s_cs[tid + 256], e1 * inv);
    }
    for (int l = tid; l < 512; l += 256) cs[b * 512 + l] = s_cs[l];
}

// ---------------------------------------------------------------------------
// Distil head, phase 1: partial pooled sums over a 64-long l-slice.
// grid (8, 512): block (sb, b). float4 gather loads, x/cs cached in LDS.
// ---------------------------------------------------------------------------
__global__ __launch_bounds__(256) void head_part_kernel(
    const int* __restrict__ xidx, const float* __restrict__ emb,
    const float* __restrict__ cs, float* __restrict__ hp) {
    int sb = blockIdx.x, b = blockIdx.y;
    int tid = threadIdx.x;
    __shared__ int s_x[64];
    __shared__ float s_c[64];
    __shared__ float s_acc[8][104];
    if (tid < 64) {
        int l = sb * 64 + tid;
        s_x[tid] = xidx[b * 512 + l];
        s_c[tid] = cs[b * 512 + l];
    }
    __syncthreads();
    int s = tid & 31, lq = tid >> 5;
    if (s < 25) {
        f32x4 a = {0.f, 0.f, 0.f, 0.f};
#pragma unroll
        for (int i = 0; i < 8; ++i) {
            int ll = lq * 8 + i;
            int row = s_x[ll];
            float cv = s_c[ll];
            f32x4 ev = *(const f32x4*)&emb[row * 100 + s * 4];
#pragma unroll
            for (int r = 0; r < 4; ++r) a[r] += ev[r] * cv;
        }
        *(f32x4*)&s_acc[lq][s * 4] = a;
    }
    __syncthreads();
    if (tid < 100) {
        float v = 0.f;
#pragma unroll
        for (int j = 0; j < 8; ++j) v += s_acc[j][tid];
        hp[(b * 8 + sb) * 100 + tid] = v;
    }
}

// ---------------------------------------------------------------------------
// Distil head, phase 2: pooled -> fc1 relu -> sigmoid head
// ---------------------------------------------------------------------------
__global__ __launch_bounds__(128) void head_fin_kernel(
    const float* __restrict__ hp, const float* __restrict__ fc1_w,
    const float* __restrict__ fc1_b, const float* __restrict__ head_w,
    const float* __restrict__ head_b, float* __restrict__ out) {
    int b = blockIdx.x, tid = threadIdx.x;
    int lane = tid & 63, wv = tid >> 6;
    __shared__ float s_pool[100];
    __shared__ float s_h2[100];
    __shared__ float s_red[2];
    if (tid < 100) {
        float a = 0.f;
#pragma unroll
        for (int sb = 0; sb < 8; ++sb) a += hp[(b * 8 + sb) * 100 + tid];
        s_pool[tid] = a * (1.f / 512.f);
    }
    __syncthreads();
    if (tid < 100) {
        float acc = fc1_b[tid];
        for (int i = 0; i < 100; ++i) acc += s_pool[i] * fc1_w[tid * 100 + i];
        s_h2[tid] = fmaxf(acc, 0.f);
    }
    __syncthreads();
    float v = (tid < 100) ? s_h2[tid] * head_w[tid] : 0.f;
#pragma unroll
    for (int off = 32; off >= 1; off >>= 1) v += __shfl_xor(v, off, 64);
    if (lane == 0) s_red[wv] = v;
    __syncthreads();
    if (tid == 0) {
        float z = s_red[0] + s_red[1] + head_b[0];
        out[b] = 1.f / (1.f + expf(-z));
    }
}

// ---------------------------------------------------------------------------
extern "C" void kernel_launch(void* const* d_in, const int* in_sizes, int n_in,
                              void* d_out, int out_size, void* d_ws, size_t ws_size,
                              hipStream_t stream) {
    const int*   x   = (const int*)d_in[0];
    const float* u   = (const float*)d_in[1];
    const float* emb = (const float*)d_in[2];
    const float* c1w = (const float*)d_in[3];
    const float* c1b = (const float*)d_in[4];
    const float* giw = (const float*)d_in[5];
    const float* gib = (const float*)d_in[6];
    const float* c2w = (const float*)d_in[7];
    const float* c2b = (const float*)d_in[8];
    const float* liw = (const float*)d_in[9];
    const float* lib = (const float*)d_in[10];
    const float* c3w = (const float*)d_in[11];
    const float* c3b = (const float*)d_in[12];
    const float* c4w = (const float*)d_in[13];
    const float* c4b = (const float*)d_in[14];
    const float* f1w = (const float*)d_in[15];
    const float* f1b = (const float*)d_in[16];
    const float* hww = (const float*)d_in[17];
    const float* hbb = (const float*)d_in[18];
    float* out = (float*)d_out;

    char* ws = (char*)d_ws;
    short* hT     = (short*)(ws + 0);           // [512][512][112] bf16, later locT
    short* tT     = (short*)(ws + 58720256);    // [512][512][112] bf16
    // hpart aliases tT: written by conv1, read by pool_gate, both BEFORE conv2
    float* hpart  = (float*)(ws + 58720256);    // [512][4][112] f32
    // hp aliases tT too: written by head_part AFTER conv_li consumed tT
    float* hp     = (float*)(ws + 58720256 + 1048576);  // [512][8][100] f32
    short* A1     = (short*)(ws + 117440512);   // 11*448*16 B
    short* A2     = (short*)(ws + 117519360);
    short* A3     = (short*)(ws + 117598208);
    short* A4     = (short*)(ws + 117677056);   // 4*448*16 B
    float* zg     = (float*)(ws + 117705728);   // [512][112] f32
    float* logits = (float*)(ws + 117935104);   // [512][512] f32
    short* locT = hT;  // h dead after conv2; reuse

    pack_A_kernel<<<77, 64, 0, stream>>>(c1w, A1, 0);
    pack_A_kernel<<<77, 64, 0, stream>>>(c2w, A2, 0);
    pack_A_kernel<<<77, 64, 0, stream>>>(liw, A3, 0);
    pack_A_kernel<<<28, 64, 0, stream>>>(c3w, A4, 1);

    dim3 cgrid(4, 512);
    size_t smem3 = 130 * 120 * 2 + 1792;  // 32992 B -> 4 blocks/CU
    size_t smem1 = 128 * 120 * 2 + 1792;  // 32512 B

    conv_mfma_kernel<3, 11, true, false, true><<<cgrid, 256, smem3, stream>>>(
        nullptr, emb, x, A1, c1b, nullptr, nullptr, nullptr, hT, nullptr, hpart);
    pool_gate_kernel<<<512, 128, 0, stream>>>(hpart, giw, gib, c3w, c3b, zg);
    conv_mfma_kernel<3, 11, false, false, false><<<cgrid, 256, smem3, stream>>>(
        hT, nullptr, nullptr, A2, c2b, nullptr, nullptr, nullptr, tT, nullptr, nullptr);
    conv_mfma_kernel<3, 11, false, false, false><<<cgrid, 256, smem3, stream>>>(
        tT, nullptr, nullptr, A3, lib, nullptr, nullptr, nullptr, locT, nullptr, nullptr);
    conv_mfma_kernel<1, 4, false, true, false><<<cgrid, 256, smem1, stream>>>(
        locT, nullptr, nullptr, A4, nullptr, zg, c4w, c4b, nullptr, logits, nullptr);
    sampler_kernel<<<512, 256, 0, stream>>>(u, logits, out + 512);
    head_part_kernel<<<dim3(8, 512), 256, 0, stream>>>(x, emb, out + 512, hp);
    head_fin_kernel<<<512, 128, 0, stream>>>(hp, f1w, f1b, hww, hbb, out);
}

// Round 3
// 353.415 us; speedup vs baseline: 1.5250x; 1.0125x over previous
//
#include <hip/hip_runtime.h>
#include <math.h>

#define DEV __device__ __forceinline__

typedef __attribute__((ext_vector_type(8))) short short8;
typedef __attribute__((ext_vector_type(4))) short short4v;
typedef __attribute__((ext_vector_type(4))) float f32x4;

DEV short f2bf(float f) {
    unsigned u = __builtin_bit_cast(unsigned, f);
    unsigned r = (u + 0x7fffu + ((u >> 16) & 1u)) >> 16;
    return (short)r;
}

// ---------------------------------------------------------------------------
// Pack all four conv weights into MFMA A-fragment order (one dispatch).
// dst[((ks*7+mt)*64+lane)*8 + j] = W[f=mt*16+(lane&15)][kappa=ks*32+(lane>>4)*8+j]
// mode 0: 3-tap conv, w [100][100][3], kappa = dk*112 + c  (K = 336, padded 352)
// mode 1: conv3 loc-half, w [100][200], kappa = c (use cols 100..199), K pad 128
// ---------------------------------------------------------------------------
__global__ __launch_bounds__(64) void pack_all_kernel(
    const float* __restrict__ c1w, const float* __restrict__ c2w,
    const float* __restrict__ liw, const float* __restrict__ c3w,
    short* __restrict__ A1, short* __restrict__ A2,
    short* __restrict__ A3, short* __restrict__ A4) {
    int bx = blockIdx.x;
    const float* w; short* dst; int mode, lbx;
    if (bx < 77)       { w = c1w; dst = A1; mode = 0; lbx = bx; }
    else if (bx < 154) { w = c2w; dst = A2; mode = 0; lbx = bx - 77; }
    else if (bx < 231) { w = liw; dst = A3; mode = 0; lbx = bx - 154; }
    else               { w = c3w; dst = A4; mode = 1; lbx = bx - 231; }
    int ks = lbx / 7, mt = lbx - ks * 7;
    int lane = threadIdx.x;
    int f = mt * 16 + (lane & 15);
    int kb = ks * 32 + (lane >> 4) * 8;
    short8 v;
#pragma unroll
    for (int j = 0; j < 8; ++j) {
        int kk = kb + j;
        float val = 0.f;
        if (f < 100) {
            if (mode == 0) {
                int dk = kk / 112, c = kk - dk * 112;
                if (dk < 3 && c < 100) val = w[(f * 100 + c) * 3 + dk];
            } else {
                if (kk < 100) val = w[f * 200 + 100 + kk];
            }
        }
        v[j] = f2bf(val);
    }
    *(short8*)&dst[(lbx * 64 + lane) * 8] = v;
}

// ---------------------------------------------------------------------------
// One 3-tap conv pass on LDS tiles (stride 120 shorts, 136 rows).
// Wave wv owns nt tiles {wv, wv+6}. A-frags from global (L2) with ping-pong
// prefetch. Row reads clamped to <=135 (clamped rows feed only discarded
// outputs). Stores masked to j<136 and zeroed outside l in [0,512).
// POOL: per-wave partial sums of relu vals for l in [l0,l0+128) -> hpart.
// TO_GLOBAL: store to gout (locT row base), rows j<=127 only (NT=8).
// ---------------------------------------------------------------------------
template<bool POOL, bool TO_GLOBAL>
DEV void conv3tap(const short* __restrict__ Ap, const float* __restrict__ bias,
                  const short* s_src, short* s_dst, short* __restrict__ gout,
                  int NT, int row0l, int l0, int pbase,
                  float* __restrict__ hpart, int lane, int wv) {
    const int q = lane >> 4, n = lane & 15;
    const int nt0 = wv, nt1 = wv + 6;
    const bool has1 = (nt1 < NT);
    const f32x4 z4 = {0.f, 0.f, 0.f, 0.f};
    f32x4 acc[2][7];
#pragma unroll
    for (int mt = 0; mt < 7; ++mt) { acc[0][mt] = z4; acc[1][mt] = z4; }
    short8 a[2][7];
#pragma unroll
    for (int mt = 0; mt < 7; ++mt)
        a[0][mt] = *(const short8*)&Ap[(mt * 64 + lane) * 8];
#pragma unroll
    for (int ks = 0; ks < 11; ++ks) {
        const int cur = ks & 1;
        if (ks < 10) {
#pragma unroll
            for (int mt = 0; mt < 7; ++mt)
                a[cur ^ 1][mt] = *(const short8*)&Ap[((ks + 1) * 448 + mt * 64 + lane) * 8];
        }
        int oct = ks * 4 + q, dk, c0;
        if (oct >= 42) { dk = 0; c0 = 0; }   // zero-padded kappa; A is 0 there
        else { dk = oct / 14; c0 = (oct - dk * 14) * 8; }
        int r0 = nt0 * 16 + n + dk; if (r0 > 135) r0 = 135;
        short8 bf0 = *(const short8*)&s_src[r0 * 120 + c0];
        short8 bf1;
        if (has1) {
            int r1 = nt1 * 16 + n + dk; if (r1 > 135) r1 = 135;
            bf1 = *(const short8*)&s_src[r1 * 120 + c0];
        }
#pragma unroll
        for (int mt = 0; mt < 7; ++mt) {
            acc[0][mt] = __builtin_amdgcn_mfma_f32_16x16x32_bf16(a[cur][mt], bf0, acc[0][mt], 0, 0, 0);
            if (has1)
                acc[1][mt] = __builtin_amdgcn_mfma_f32_16x16x32_bf16(a[cur][mt], bf1, acc[1][mt], 0, 0, 0);
        }
    }
    f32x4 psum[7];
    if constexpr (POOL) {
#pragma unroll
        for (int mt = 0; mt < 7; ++mt) psum[mt] = z4;
    }
#pragma unroll
    for (int t = 0; t < 2; ++t) {
        if (t == 1 && !has1) break;
        const int nt = t ? nt1 : nt0;
        const int j = nt * 16 + n;
        const int l = row0l + j;
        const bool lok = (l >= 0) && (l < 512);
        const bool pok = POOL && (l >= l0) && (l < l0 + 128);
#pragma unroll
        for (int mt = 0; mt < 7; ++mt) {
            const int fb = mt * 16 + q * 4;
            f32x4 bs = (fb < 100) ? *(const f32x4*)&bias[fb] : z4;
            short4v pk;
#pragma unroll
            for (int r = 0; r < 4; ++r) {
                float v = fmaxf(acc[t][mt][r] + bs[r], 0.f);
                v = lok ? v : 0.f;
                pk[r] = f2bf(v);
                if constexpr (POOL) { if (pok) psum[mt][r] += v; }
            }
            if constexpr (TO_GLOBAL) {
                *(short4v*)&gout[j * 112 + fb] = pk;
            } else {
                if (j < 136) *(short4v*)&s_dst[j * 120 + fb] = pk;
            }
        }
    }
    if constexpr (POOL) {
#pragma unroll
        for (int mt = 0; mt < 7; ++mt)
#pragma unroll
            for (int off = 1; off <= 8; off <<= 1)
#pragma unroll
                for (int r = 0; r < 4; ++r)
                    psum[mt][r] += __shfl_xor(psum[mt][r], off, 64);
        if (n == 0) {
#pragma unroll
            for (int mt = 0; mt < 7; ++mt)
                *(f32x4*)&hpart[(pbase * 6 + wv) * 112 + mt * 16 + q * 4] = psum[mt];
        }
    }
}

// ---------------------------------------------------------------------------
// Fused conv1 -> conv2 -> li in ONE kernel. Block: (bx,b), 384 threads
// (6 waves), l-tile = 128 outputs with halo recompute.
// s_e rows: l = l0-3+j, j=0..135.  h rows: l = l0-2+j.  c2 (alias s_e):
// l = l0-1+j.  loc: l = l0+j -> global.
// ---------------------------------------------------------------------------
__global__ __launch_bounds__(384, 3) void fused_conv_kernel(
    const int* __restrict__ xidx, const float* __restrict__ emb,
    const short* __restrict__ A1, const short* __restrict__ A2,
    const short* __restrict__ A3,
    const float* __restrict__ b1, const float* __restrict__ b2,
    const float* __restrict__ b3,
    short* __restrict__ locT, float* __restrict__ hpart) {
    extern __shared__ char smem[];
    short* s_e = (short*)smem;                   // [136][120], later c2
    short* s_h = (short*)(smem + 136 * 120 * 2); // [136][120]
    int*   s_x = (int*)s_h;                      // alias: dead before h written
    const int tid = threadIdx.x;
    const int b = blockIdx.y, bx = blockIdx.x, l0 = bx * 128;
    const int lane = tid & 63, wv = tid >> 6;

    if (tid < 136) {
        int lg = l0 - 3 + tid;
        s_x[tid] = (lg >= 0 && lg < 512) ? xidx[b * 512 + lg] : -1;
    }
    __syncthreads();
    {
        int c4 = tid & 31, j0 = tid >> 5;   // 12 rows per pass
#pragma unroll
        for (int p = 0; p < 12; ++p) {
            int j = p * 12 + j0;
            if (j < 136) {
                if (c4 < 25) {
                    int row = s_x[j];
                    short4v v = {0, 0, 0, 0};
                    if (row >= 0) {
                        f32x4 ev = *(const f32x4*)&emb[row * 100 + c4 * 4];
#pragma unroll
                        for (int r = 0; r < 4; ++r) v[r] = f2bf(ev[r]);
                    }
                    *(short4v*)&s_e[j * 120 + c4 * 4] = v;
                } else if (c4 < 30) {
                    short4v zz = {0, 0, 0, 0};
                    *(short4v*)&s_e[j * 120 + 100 + (c4 - 25) * 4] = zz;
                }
            }
        }
    }
    __syncthreads();
    // conv1: e -> h (+ pool partials)
    conv3tap<true, false>(A1, b1, s_e, s_h, nullptr, 9, l0 - 2, l0,
                          b * 4 + bx, hpart, lane, wv);
    __syncthreads();
    // conv2: h -> c2 (into s_e)
    conv3tap<false, false>(A2, b2, s_h, s_e, nullptr, 9, l0 - 1, l0,
                           0, nullptr, lane, wv);
    __syncthreads();
    // li: c2 -> loc (global)
    conv3tap<false, true>(A3, b3, s_e, nullptr,
                          locT + ((size_t)b * 512 + l0) * 112, 8, l0, l0,
                          0, nullptr, lane, wv);
}

// ---------------------------------------------------------------------------
// conv3 (1x1, loc half) + conv4 fused -> logits. N=256 tile (16 nt, 4 waves
// x 4 nt), register-batched staging, A ping-pong prefetch (NKS=4).
// ---------------------------------------------------------------------------
__global__ __launch_bounds__(256, 2) void conv3_logits_kernel(
    const short* __restrict__ locT, const short* __restrict__ A4,
    const float* __restrict__ zg, const float* __restrict__ w4,
    const float* __restrict__ b4, float* __restrict__ logits) {
    extern __shared__ char smem[];
    short* s_in = (short*)smem;   // [256][120]
    const int tid = threadIdx.x;
    const int b = blockIdx.y, l0r = blockIdx.x * 256;
    const int lane = tid & 63, wv = tid >> 6;
    const int q = lane >> 4, n = lane & 15;

    // stage 256 rows x 112 ch: 3584 short8 chunks, batched 7 loads at a time
#pragma unroll
    for (int g = 0; g < 2; ++g) {
        short8 tmp[7];
#pragma unroll
        for (int p = 0; p < 7; ++p) {
            int idx = tid + (g * 7 + p) * 256;
            int j = idx / 14, c8 = idx - j * 14;
            tmp[p] = *(const short8*)&locT[((size_t)b * 512 + l0r + j) * 112 + c8 * 8];
        }
#pragma unroll
        for (int p = 0; p < 7; ++p) {
            int idx = tid + (g * 7 + p) * 256;
            int j = idx / 14, c8 = idx - j * 14;
            *(short8*)&s_in[j * 120 + c8 * 8] = tmp[p];
        }
    }
    __syncthreads();

    const f32x4 z4 = {0.f, 0.f, 0.f, 0.f};
    f32x4 acc[4][7];
#pragma unroll
    for (int t = 0; t < 4; ++t)
#pragma unroll
        for (int mt = 0; mt < 7; ++mt) acc[t][mt] = z4;
    short8 a[2][7];
#pragma unroll
    for (int mt = 0; mt < 7; ++mt)
        a[0][mt] = *(const short8*)&A4[(mt * 64 + lane) * 8];
#pragma unroll
    for (int ks = 0; ks < 4; ++ks) {
        const int cur = ks & 1;
        if (ks < 3) {
#pragma unroll
            for (int mt = 0; mt < 7; ++mt)
                a[cur ^ 1][mt] = *(const short8*)&A4[((ks + 1) * 448 + mt * 64 + lane) * 8];
        }
        int c0 = (ks * 4 + q) * 8;
        if (c0 > 104) c0 = 104;   // A zero for kappa>=100
        short8 bf[4];
#pragma unroll
        for (int t = 0; t < 4; ++t)
            bf[t] = *(const short8*)&s_in[((wv + 4 * t) * 16 + n) * 120 + c0];
#pragma unroll
        for (int mt = 0; mt < 7; ++mt)
#pragma unroll
            for (int t = 0; t < 4; ++t)
                acc[t][mt] = __builtin_amdgcn_mfma_f32_16x16x32_bf16(a[cur][mt], bf[t], acc[t][mt], 0, 0, 0);
    }
#pragma unroll
    for (int t = 0; t < 4; ++t) {
        float part = 0.f;
#pragma unroll
        for (int mt = 0; mt < 7; ++mt) {
            const int fb = mt * 16 + q * 4;
            f32x4 w4v = (fb < 100) ? *(const f32x4*)&w4[fb] : z4;
            f32x4 zgv = *(const f32x4*)&zg[b * 112 + fb];
#pragma unroll
            for (int r = 0; r < 4; ++r)
                part += fmaxf(acc[t][mt][r] + zgv[r], 0.f) * w4v[r];
        }
        part += __shfl_xor(part, 16, 64);
        part += __shfl_xor(part, 32, 64);
        if (q == 0)
            logits[b * 512 + l0r + (wv + 4 * t) * 16 + n] = part + b4[0];
    }
}

// ---------------------------------------------------------------------------
// Finish pool: hm = sum over 24 wave-partials / 512, gate MLP, fold g:
// zg[b,f] = conv3_b[f] + sum_h g[b,h] * w3[f][h]   (f>=100 -> 0)
// ---------------------------------------------------------------------------
__global__ __launch_bounds__(128) void pool_gate_kernel(
    const float* __restrict__ hpart, const float* __restrict__ gi_w,
    const float* __restrict__ gi_b, const float* __restrict__ w3,
    const float* __restrict__ b3, float* __restrict__ zg) {
    int b = blockIdx.x, tid = threadIdx.x;
    __shared__ float s_hm[112];
    __shared__ float s_g[100];
    if (tid < 112) {
        float a = 0.f;
#pragma unroll
        for (int s = 0; s < 24; ++s) a += hpart[(b * 24 + s) * 112 + tid];
        s_hm[tid] = a * (1.f / 512.f);
    }
    __syncthreads();
    if (tid < 100) {
        float a = gi_b[tid];
        for (int f = 0; f < 100; ++f) a += s_hm[f] * gi_w[tid * 100 + f];
        s_g[tid] = fmaxf(a, 0.f);
    }
    __syncthreads();
    if (tid < 112) {
        float a = 0.f;
        if (tid < 100) {
            a = b3[tid];
            for (int h = 0; h < 100; ++h) a += s_g[h] * w3[tid * 200 + h];
        }
        zg[b * 112 + tid] = a;
    }
}

// ---------------------------------------------------------------------------
// Gumbel top-k sampler: csamples[b,l] = max_k softmax_l((gumbel+logit)/T)
// All 20 u-loads preissued (MLP), then 10 barrier-coupled reduction rounds.
// ---------------------------------------------------------------------------
__global__ __launch_bounds__(256) void sampler_kernel(
    const float* __restrict__ u, const float* __restrict__ logits,
    float* __restrict__ cs) {
    const float EPSV = 1.1920929e-07f;
    int b = blockIdx.x, tid = threadIdx.x;
    int lane = tid & 63, wv = tid >> 6;
    __shared__ float s_log[512], s_cs[512], s_red[8];
    float uu[20];
#pragma unroll
    for (int k = 0; k < 10; ++k) {
        uu[k * 2]     = u[(b * 10 + k) * 512 + tid];
        uu[k * 2 + 1] = u[(b * 10 + k) * 512 + tid + 256];
    }
    for (int l = tid; l < 512; l += 256) { s_log[l] = logits[b * 512 + l]; s_cs[l] = 0.f; }
    __syncthreads();
    for (int k = 0; k < 10; ++k) {
        float nz[2];
#pragma unroll
        for (int i = 0; i < 2; ++i) {
            int l = tid + i * 256;
            float vv = fminf(fmaxf(uu[k * 2 + i], EPSV), 1.f - EPSV);
            float g = -logf(-logf(vv));
            nz[i] = (g + s_log[l]) * (1.f / 0.3f);
        }
        float m = fmaxf(nz[0], nz[1]);
#pragma unroll
        for (int off = 32; off >= 1; off >>= 1) m = fmaxf(m, __shfl_xor(m, off, 64));
        if (lane == 0) s_red[wv] = m;
        __syncthreads();
        m = fmaxf(fmaxf(s_red[0], s_red[1]), fmaxf(s_red[2], s_red[3]));
        float e0 = expf(nz[0] - m), e1 = expf(nz[1] - m);
        float s = e0 + e1;
#pragma unroll
        for (int off = 32; off >= 1; off >>= 1) s += __shfl_xor(s, off, 64);
        if (lane == 0) s_red[4 + wv] = s;
        __syncthreads();
        float inv = 1.f / (s_red[4] + s_red[5] + s_red[6] + s_red[7]);
        s_cs[tid]       = fmaxf(s_cs[tid],       e0 * inv);
        s_cs[tid + 256] = fmaxf(s_cs[tid + 256], e1 * inv);
    }
    for (int l = tid; l < 512; l += 256) cs[b * 512 + l] = s_cs[l];
}

// ---------------------------------------------------------------------------
// Distil head, phase 1: partial pooled sums over a 64-long l-slice.
// ---------------------------------------------------------------------------
__global__ __launch_bounds__(256) void head_part_kernel(
    const int* __restrict__ xidx, const float* __restrict__ emb,
    const float* __restrict__ cs, float* __restrict__ hp) {
    int sb = blockIdx.x, b = blockIdx.y;
    int tid = threadIdx.x;
    __shared__ int s_x[64];
    __shared__ float s_c[64];
    __shared__ float s_acc[8][104];
    if (tid < 64) {
        int l = sb * 64 + tid;
        s_x[tid] = xidx[b * 512 + l];
        s_c[tid] = cs[b * 512 + l];
    }
    __syncthreads();
    int s = tid & 31, lq = tid >> 5;
    if (s < 25) {
        f32x4 a = {0.f, 0.f, 0.f, 0.f};
#pragma unroll
        for (int i = 0; i < 8; ++i) {
            int ll = lq * 8 + i;
            int row = s_x[ll];
            float cv = s_c[ll];
            f32x4 ev = *(const f32x4*)&emb[row * 100 + s * 4];
#pragma unroll
            for (int r = 0; r < 4; ++r) a[r] += ev[r] * cv;
        }
        *(f32x4*)&s_acc[lq][s * 4] = a;
    }
    __syncthreads();
    if (tid < 100) {
        float v = 0.f;
#pragma unroll
        for (int j = 0; j < 8; ++j) v += s_acc[j][tid];
        hp[(b * 8 + sb) * 100 + tid] = v;
    }
}

// ---------------------------------------------------------------------------
// Distil head, phase 2: pooled -> fc1 relu -> sigmoid head
// ---------------------------------------------------------------------------
__global__ __launch_bounds__(128) void head_fin_kernel(
    const float* __restrict__ hp, const float* __restrict__ fc1_w,
    const float* __restrict__ fc1_b, const float* __restrict__ head_w,
    const float* __restrict__ head_b, float* __restrict__ out) {
    int b = blockIdx.x, tid = threadIdx.x;
    int lane = tid & 63, wv = tid >> 6;
    __shared__ float s_pool[100];
    __shared__ float s_h2[100];
    __shared__ float s_red[2];
    if (tid < 100) {
        float a = 0.f;
#pragma unroll
        for (int sb = 0; sb < 8; ++sb) a += hp[(b * 8 + sb) * 100 + tid];
        s_pool[tid] = a * (1.f / 512.f);
    }
    __syncthreads();
    if (tid < 100) {
        float acc = fc1_b[tid];
        for (int i = 0; i < 100; ++i) acc += s_pool[i] * fc1_w[tid * 100 + i];
        s_h2[tid] = fmaxf(acc, 0.f);
    }
    __syncthreads();
    float v = (tid < 100) ? s_h2[tid] * head_w[tid] : 0.f;
#pragma unroll
    for (int off = 32; off >= 1; off >>= 1) v += __shfl_xor(v, off, 64);
    if (lane == 0) s_red[wv] = v;
    __syncthreads();
    if (tid == 0) {
        float z = s_red[0] + s_red[1] + head_b[0];
        out[b] = 1.f / (1.f + expf(-z));
    }
}

// ---------------------------------------------------------------------------
extern "C" void kernel_launch(void* const* d_in, const int* in_sizes, int n_in,
                              void* d_out, int out_size, void* d_ws, size_t ws_size,
                              hipStream_t stream) {
    const int*   x   = (const int*)d_in[0];
    const float* u   = (const float*)d_in[1];
    const float* emb = (const float*)d_in[2];
    const float* c1w = (const float*)d_in[3];
    const float* c1b = (const float*)d_in[4];
    const float* giw = (const float*)d_in[5];
    const float* gib = (const float*)d_in[6];
    const float* c2w = (const float*)d_in[7];
    const float* c2b = (const float*)d_in[8];
    const float* liw = (const float*)d_in[9];
    const float* lib = (const float*)d_in[10];
    const float* c3w = (const float*)d_in[11];
    const float* c3b = (const float*)d_in[12];
    const float* c4w = (const float*)d_in[13];
    const float* c4b = (const float*)d_in[14];
    const float* f1w = (const float*)d_in[15];
    const float* f1b = (const float*)d_in[16];
    const float* hww = (const float*)d_in[17];
    const float* hbb = (const float*)d_in[18];
    float* out = (float*)d_out;

    char* ws = (char*)d_ws;
    short* locT   = (short*)(ws + 0);           // [512][512][112] bf16
    short* A1     = (short*)(ws + 58720256);    // 11*448*16 B
    short* A2     = (short*)(ws + 58799104);
    short* A3     = (short*)(ws + 58877952);
    short* A4     = (short*)(ws + 58956800);    // 4*448*16 B
    float* zg     = (float*)(ws + 58985472);    // [512][112]
    float* logits = (float*)(ws + 59214848);    // [512][512]
    float* hpart  = (float*)(ws + 60263424);    // [512][4][6][112]
    float* hp     = (float*)(ws + 65768448);    // [512][8][100]

    pack_all_kernel<<<259, 64, 0, stream>>>(c1w, c2w, liw, c3w, A1, A2, A3, A4);

    size_t smemA = 2 * 136 * 120 * 2;   // 65280 B
    fused_conv_kernel<<<dim3(4, 512), 384, smemA, stream>>>(
        x, emb, A1, A2, A3, c1b, c2b, lib, locT, hpart);
    pool_gate_kernel<<<512, 128, 0, stream>>>(hpart, giw, gib, c3w, c3b, zg);
    size_t smemB = 256 * 120 * 2;       // 61440 B
    conv3_logits_kernel<<<dim3(2, 512), 256, smemB, stream>>>(
        locT, A4, zg, c4w, c4b, logits);
    sampler_kernel<<<512, 256, 0, stream>>>(u, logits, out + 512);
    head_part_kernel<<<dim3(8, 512), 256, 0, stream>>>(x, emb, out + 512, hp);
    head_fin_kernel<<<512, 128, 0, stream>>>(hp, f1w, f1b, hww, hbb, out);
}

// Round 4
// 330.804 us; speedup vs baseline: 1.6292x; 1.0684x over previous
//
#include <hip/hip_runtime.h>
#include <math.h>

#define DEV __device__ __forceinline__

typedef __attribute__((ext_vector_type(8))) short short8;
typedef __attribute__((ext_vector_type(4))) short short4v;
typedef __attribute__((ext_vector_type(4))) float f32x4;

// LDS row stride in shorts: 136 (272 B). W=68 words; 68 mod 32 = 4 =>
// 16-lane b128 reads spread uniformly, 2 lanes per 4-bank group (free).
#define SSTR 136

DEV short f2bf(float f) {
    unsigned u = __builtin_bit_cast(unsigned, f);
    unsigned r = (u + 0x7fffu + ((u >> 16) & 1u)) >> 16;
    return (short)r;
}

// ---------------------------------------------------------------------------
// Pack all four conv weights into MFMA A-fragment order (one dispatch).
// dst[((ks*7+mt)*64+lane)*8 + j] = W[f=mt*16+(lane&15)][kappa=ks*32+(lane>>4)*8+j]
// mode 0: 3-tap conv, w [100][100][3], kappa = dk*112 + c  (K = 336, padded 352)
// mode 1: conv3 loc-half, w [100][200], kappa = c (use cols 100..199), K pad 128
// ---------------------------------------------------------------------------
__global__ __launch_bounds__(64) void pack_all_kernel(
    const float* __restrict__ c1w, const float* __restrict__ c2w,
    const float* __restrict__ liw, const float* __restrict__ c3w,
    short* __restrict__ A1, short* __restrict__ A2,
    short* __restrict__ A3, short* __restrict__ A4) {
    int bx = blockIdx.x;
    const float* w; short* dst; int mode, lbx;
    if (bx < 77)       { w = c1w; dst = A1; mode = 0; lbx = bx; }
    else if (bx < 154) { w = c2w; dst = A2; mode = 0; lbx = bx - 77; }
    else if (bx < 231) { w = liw; dst = A3; mode = 0; lbx = bx - 154; }
    else               { w = c3w; dst = A4; mode = 1; lbx = bx - 231; }
    int ks = lbx / 7, mt = lbx - ks * 7;
    int lane = threadIdx.x;
    int f = mt * 16 + (lane & 15);
    int kb = ks * 32 + (lane >> 4) * 8;
    short8 v;
#pragma unroll
    for (int j = 0; j < 8; ++j) {
        int kk = kb + j;
        float val = 0.f;
        if (f < 100) {
            if (mode == 0) {
                int dk = kk / 112, c = kk - dk * 112;
                if (dk < 3 && c < 100) val = w[(f * 100 + c) * 3 + dk];
            } else {
                if (kk < 100) val = w[f * 200 + 100 + kk];
            }
        }
        v[j] = f2bf(val);
    }
    *(short8*)&dst[(lbx * 64 + lane) * 8] = v;
}

// ---------------------------------------------------------------------------
// One 3-tap conv pass on LDS tiles (stride SSTR, 72 rows, valid rows 0..69).
// 4 waves; wave wv owns nt tiles {wv, wv+4} (second only if < NT).
// A-frags from global (L2-resident), single-buffer; full ks unroll lets the
// compiler pipeline the 77 loads against MFMA under the 128-VGPR cap.
// Reads clamp rows to <=69; stores mask j<70; l outside [0,512) zeroed
// (matches F.conv1d zero padding).
// POOL: partial sums of relu for l in [l0,l0+64) -> hpart (per wave).
// TO_GLOBAL: store rows j<64 to gout.
// ---------------------------------------------------------------------------
template<bool POOL, bool TO_GLOBAL>
DEV void conv3tap(const short* __restrict__ Ap, const float* __restrict__ bias,
                  const short* s_src, short* s_dst, short* __restrict__ gout,
                  int NT, int row0l, int l0, int pbase,
                  float* __restrict__ hpart, int lane, int wv) {
    const int q = lane >> 4, n = lane & 15;
    const int nt0 = wv, nt1 = wv + 4;
    const bool has1 = (nt1 < NT);
    const f32x4 z4 = {0.f, 0.f, 0.f, 0.f};
    f32x4 acc[2][7];
#pragma unroll
    for (int mt = 0; mt < 7; ++mt) { acc[0][mt] = z4; acc[1][mt] = z4; }
#pragma unroll
    for (int ks = 0; ks < 11; ++ks) {
        short8 a[7];
#pragma unroll
        for (int mt = 0; mt < 7; ++mt)
            a[mt] = *(const short8*)&Ap[(ks * 448 + mt * 64 + lane) * 8];
        int oct = ks * 4 + q, dk, c0;
        if (oct >= 42) { dk = 0; c0 = 0; }   // zero-padded kappa; A is 0 there
        else { dk = oct / 14; c0 = (oct - dk * 14) * 8; }
        int r0 = nt0 * 16 + n + dk; if (r0 > 69) r0 = 69;
        short8 bf0 = *(const short8*)&s_src[r0 * SSTR + c0];
        short8 bf1;
        if (has1) {
            int r1 = nt1 * 16 + n + dk; if (r1 > 69) r1 = 69;
            bf1 = *(const short8*)&s_src[r1 * SSTR + c0];
        }
#pragma unroll
        for (int mt = 0; mt < 7; ++mt) {
            acc[0][mt] = __builtin_amdgcn_mfma_f32_16x16x32_bf16(a[mt], bf0, acc[0][mt], 0, 0, 0);
            if (has1)
                acc[1][mt] = __builtin_amdgcn_mfma_f32_16x16x32_bf16(a[mt], bf1, acc[1][mt], 0, 0, 0);
        }
    }
    f32x4 psum[7];
    if constexpr (POOL) {
#pragma unroll
        for (int mt = 0; mt < 7; ++mt) psum[mt] = z4;
    }
#pragma unroll
    for (int t = 0; t < 2; ++t) {
        if (t == 1 && !has1) break;
        const int nt = t ? nt1 : nt0;
        const int j = nt * 16 + n;
        const int l = row0l + j;
        const bool lok = (l >= 0) && (l < 512);
        const bool pok = POOL && (l >= l0) && (l < l0 + 64);
#pragma unroll
        for (int mt = 0; mt < 7; ++mt) {
            const int fb = mt * 16 + q * 4;
            f32x4 bs = (fb < 100) ? *(const f32x4*)&bias[fb] : z4;
            short4v pk;
#pragma unroll
            for (int r = 0; r < 4; ++r) {
                float v = fmaxf(acc[t][mt][r] + bs[r], 0.f);
                v = lok ? v : 0.f;
                pk[r] = f2bf(v);
                if constexpr (POOL) { if (pok) psum[mt][r] += v; }
            }
            if constexpr (TO_GLOBAL) {
                if (j < 64) *(short4v*)&gout[j * 112 + fb] = pk;
            } else {
                if (j < 70) *(short4v*)&s_dst[j * SSTR + fb] = pk;
            }
        }
    }
    if constexpr (POOL) {
#pragma unroll
        for (int mt = 0; mt < 7; ++mt)
#pragma unroll
            for (int off = 1; off <= 8; off <<= 1)
#pragma unroll
                for (int r = 0; r < 4; ++r)
                    psum[mt][r] += __shfl_xor(psum[mt][r], off, 64);
        if (n == 0) {
#pragma unroll
            for (int mt = 0; mt < 7; ++mt)
                *(f32x4*)&hpart[(pbase * 4 + wv) * 112 + mt * 16 + q * 4] = psum[mt];
        }
    }
}

// ---------------------------------------------------------------------------
// Fused conv1 -> conv2 -> li, 64-wide l-tile, 256 threads (4 waves).
// LDS 2*72*SSTR*2 = 39168 B -> 4 blocks/CU (16 waves = 50% occ).
// s_e rows: l = l0-3+j (j=0..69). h: l = l0-2+j. c2 (alias s_e): l = l0-1+j.
// loc: l = l0+j -> global.
// ---------------------------------------------------------------------------
__global__ __launch_bounds__(256, 4) void fused_conv_kernel(
    const int* __restrict__ xidx, const float* __restrict__ emb,
    const short* __restrict__ A1, const short* __restrict__ A2,
    const short* __restrict__ A3,
    const float* __restrict__ b1, const float* __restrict__ b2,
    const float* __restrict__ b3,
    short* __restrict__ locT, float* __restrict__ hpart) {
    extern __shared__ char smem[];
    short* s_e = (short*)smem;                    // [72][SSTR], later c2
    short* s_h = (short*)(smem + 72 * SSTR * 2);  // [72][SSTR]
    const int tid = threadIdx.x;
    const int b = blockIdx.y, bx = blockIdx.x, l0 = bx * 64;
    const int lane = tid & 63, wv = tid >> 6;

    // stage e: 70 rows x 28 chunks (25 gather + 3 zero-pad cols 100..111).
    // x read straight from global: 28 lanes share an address -> L1 broadcast.
#pragma unroll
    for (int idx = tid; idx < 70 * 28; idx += 256) {
        int j = idx / 28, c4 = idx - j * 28;
        int lg = l0 - 3 + j;
        short4v v = {0, 0, 0, 0};
        if (c4 < 25) {
            if (lg >= 0 && lg < 512) {
                int row = xidx[b * 512 + lg];
                f32x4 ev = *(const f32x4*)&emb[row * 100 + c4 * 4];
#pragma unroll
                for (int r = 0; r < 4; ++r) v[r] = f2bf(ev[r]);
            }
        }
        *(short4v*)&s_e[j * SSTR + c4 * 4] = v;
    }
    __syncthreads();
    // conv1: e -> h (+ pool partials over l in [l0,l0+64))
    conv3tap<true, false>(A1, b1, s_e, s_h, nullptr, 5, l0 - 2, l0,
                          b * 8 + bx, hpart, lane, wv);
    __syncthreads();
    // conv2: h -> c2 (into s_e)
    conv3tap<false, false>(A2, b2, s_h, s_e, nullptr, 5, l0 - 1, l0,
                           0, nullptr, lane, wv);
    __syncthreads();
    // li: c2 -> loc (global)
    conv3tap<false, true>(A3, b3, s_e, nullptr,
                          locT + ((size_t)b * 512 + l0) * 112, 4, l0, l0,
                          0, nullptr, lane, wv);
}

// ---------------------------------------------------------------------------
// conv3 (1x1, loc half) + conv4 fused -> logits. 128-l tile, 4 waves x
// 2 nt each; LDS 128*SSTR*2 = 34816 B -> 4 blocks/CU.
// ---------------------------------------------------------------------------
__global__ __launch_bounds__(256, 4) void conv3_logits_kernel(
    const short* __restrict__ locT, const short* __restrict__ A4,
    const float* __restrict__ zg, const float* __restrict__ w4,
    const float* __restrict__ b4, float* __restrict__ logits) {
    extern __shared__ char smem[];
    short* s_in = (short*)smem;   // [128][SSTR]
    const int tid = threadIdx.x;
    const int b = blockIdx.y, l0r = blockIdx.x * 128;
    const int lane = tid & 63, wv = tid >> 6;
    const int q = lane >> 4, n = lane & 15;

    // stage 128 rows x 112 ch: 1792 short8 chunks, register-batched
    {
        short8 tmp[7];
#pragma unroll
        for (int p = 0; p < 7; ++p) {
            int idx = tid + p * 256;
            int j = idx / 14, c8 = idx - j * 14;
            tmp[p] = *(const short8*)&locT[((size_t)b * 512 + l0r + j) * 112 + c8 * 8];
        }
#pragma unroll
        for (int p = 0; p < 7; ++p) {
            int idx = tid + p * 256;
            int j = idx / 14, c8 = idx - j * 14;
            *(short8*)&s_in[j * SSTR + c8 * 8] = tmp[p];
        }
    }
    __syncthreads();

    const f32x4 z4 = {0.f, 0.f, 0.f, 0.f};
    f32x4 acc[2][7];
#pragma unroll
    for (int t = 0; t < 2; ++t)
#pragma unroll
        for (int mt = 0; mt < 7; ++mt) acc[t][mt] = z4;
#pragma unroll
    for (int ks = 0; ks < 4; ++ks) {
        short8 a[7];
#pragma unroll
        for (int mt = 0; mt < 7; ++mt)
            a[mt] = *(const short8*)&A4[(ks * 448 + mt * 64 + lane) * 8];
        int c0 = (ks * 4 + q) * 8;
        if (c0 > 104) c0 = 104;   // A zero for kappa>=100
        short8 bf[2];
#pragma unroll
        for (int t = 0; t < 2; ++t)
            bf[t] = *(const short8*)&s_in[((wv + 4 * t) * 16 + n) * SSTR + c0];
#pragma unroll
        for (int mt = 0; mt < 7; ++mt)
#pragma unroll
            for (int t = 0; t < 2; ++t)
                acc[t][mt] = __builtin_amdgcn_mfma_f32_16x16x32_bf16(a[mt], bf[t], acc[t][mt], 0, 0, 0);
    }
#pragma unroll
    for (int t = 0; t < 2; ++t) {
        float part = 0.f;
#pragma unroll
        for (int mt = 0; mt < 7; ++mt) {
            const int fb = mt * 16 + q * 4;
            f32x4 w4v = (fb < 100) ? *(const f32x4*)&w4[fb] : z4;
            f32x4 zgv = *(const f32x4*)&zg[b * 112 + fb];
#pragma unroll
            for (int r = 0; r < 4; ++r)
                part += fmaxf(acc[t][mt][r] + zgv[r], 0.f) * w4v[r];
        }
        part += __shfl_xor(part, 16, 64);
        part += __shfl_xor(part, 32, 64);
        if (q == 0)
            logits[b * 512 + l0r + (wv + 4 * t) * 16 + n] = part + b4[0];
    }
}

// ---------------------------------------------------------------------------
// Finish pool: hm = sum over 32 wave-partials / 512, gate MLP, fold g:
// zg[b,f] = conv3_b[f] + sum_h g[b,h] * w3[f][h]   (f>=100 -> 0)
// ---------------------------------------------------------------------------
__global__ __launch_bounds__(128) void pool_gate_kernel(
    const float* __restrict__ hpart, const float* __restrict__ gi_w,
    const float* __restrict__ gi_b, const float* __restrict__ w3,
    const float* __restrict__ b3, float* __restrict__ zg) {
    int b = blockIdx.x, tid = threadIdx.x;
    __shared__ float s_hm[112];
    __shared__ float s_g[100];
    if (tid < 112) {
        float a = 0.f;
#pragma unroll
        for (int s = 0; s < 32; ++s) a += hpart[(b * 32 + s) * 112 + tid];
        s_hm[tid] = a * (1.f / 512.f);
    }
    __syncthreads();
    if (tid < 100) {
        float a = gi_b[tid];
        for (int f = 0; f < 100; ++f) a += s_hm[f] * gi_w[tid * 100 + f];
        s_g[tid] = fmaxf(a, 0.f);
    }
    __syncthreads();
    if (tid < 112) {
        float a = 0.f;
        if (tid < 100) {
            a = b3[tid];
            for (int h = 0; h < 100; ++h) a += s_g[h] * w3[tid * 200 + h];
        }
        zg[b * 112 + tid] = a;
    }
}

// ---------------------------------------------------------------------------
// Gumbel top-k sampler: csamples[b,l] = max_k softmax_l((gumbel+logit)/T)
// ---------------------------------------------------------------------------
__global__ __launch_bounds__(256) void sampler_kernel(
    const float* __restrict__ u, const float* __restrict__ logits,
    float* __restrict__ cs) {
    const float EPSV = 1.1920929e-07f;
    int b = blockIdx.x, tid = threadIdx.x;
    int lane = tid & 63, wv = tid >> 6;
    __shared__ float s_log[512], s_cs[512], s_red[8];
    float uu[20];
#pragma unroll
    for (int k = 0; k < 10; ++k) {
        uu[k * 2]     = u[(b * 10 + k) * 512 + tid];
        uu[k * 2 + 1] = u[(b * 10 + k) * 512 + tid + 256];
    }
    for (int l = tid; l < 512; l += 256) { s_log[l] = logits[b * 512 + l]; s_cs[l] = 0.f; }
    __syncthreads();
    for (int k = 0; k < 10; ++k) {
        float nz[2];
#pragma unroll
        for (int i = 0; i < 2; ++i) {
            int l = tid + i * 256;
            float vv = fminf(fmaxf(uu[k * 2 + i], EPSV), 1.f - EPSV);
            float g = -__logf(-__logf(vv));
            nz[i] = (g + s_log[l]) * (1.f / 0.3f);
        }
        float m = fmaxf(nz[0], nz[1]);
#pragma unroll
        for (int off = 32; off >= 1; off >>= 1) m = fmaxf(m, __shfl_xor(m, off, 64));
        if (lane == 0) s_red[wv] = m;
        __syncthreads();
        m = fmaxf(fmaxf(s_red[0], s_red[1]), fmaxf(s_red[2], s_red[3]));
        float e0 = __expf(nz[0] - m), e1 = __expf(nz[1] - m);
        float s = e0 + e1;
#pragma unroll
        for (int off = 32; off >= 1; off >>= 1) s += __shfl_xor(s, off, 64);
        if (lane == 0) s_red[4 + wv] = s;
        __syncthreads();
        float inv = 1.f / (s_red[4] + s_red[5] + s_red[6] + s_red[7]);
        s_cs[tid]       = fmaxf(s_cs[tid],       e0 * inv);
        s_cs[tid + 256] = fmaxf(s_cs[tid + 256], e1 * inv);
    }
    for (int l = tid; l < 512; l += 256) cs[b * 512 + l] = s_cs[l];
}

// ---------------------------------------------------------------------------
// Distil head, phase 1: partial pooled sums over a 64-long l-slice.
// ---------------------------------------------------------------------------
__global__ __launch_bounds__(256) void head_part_kernel(
    const int* __restrict__ xidx, const float* __restrict__ emb,
    const float* __restrict__ cs, float* __restrict__ hp) {
    int sb = blockIdx.x, b = blockIdx.y;
    int tid = threadIdx.x;
    __shared__ int s_x[64];
    __shared__ float s_c[64];
    __shared__ float s_acc[8][104];
    if (tid < 64) {
        int l = sb * 64 + tid;
        s_x[tid] = xidx[b * 512 + l];
        s_c[tid] = cs[b * 512 + l];
    }
    __syncthreads();
    int s = tid & 31, lq = tid >> 5;
    if (s < 25) {
        f32x4 a = {0.f, 0.f, 0.f, 0.f};
#pragma unroll
        for (int i = 0; i < 8; ++i) {
            int ll = lq * 8 + i;
            int row = s_x[ll];
            float cv = s_c[ll];
            f32x4 ev = *(const f32x4*)&emb[row * 100 + s * 4];
#pragma unroll
            for (int r = 0; r < 4; ++r) a[r] += ev[r] * cv;
        }
        *(f32x4*)&s_acc[lq][s * 4] = a;
    }
    __syncthreads();
    if (tid < 100) {
        float v = 0.f;
#pragma unroll
        for (int j = 0; j < 8; ++j) v += s_acc[j][tid];
        hp[(b * 8 + sb) * 100 + tid] = v;
    }
}

// ---------------------------------------------------------------------------
// Distil head, phase 2: pooled -> fc1 relu -> sigmoid head
// ---------------------------------------------------------------------------
__global__ __launch_bounds__(128) void head_fin_kernel(
    const float* __restrict__ hp, const float* __restrict__ fc1_w,
    const float* __restrict__ fc1_b, const float* __restrict__ head_w,
    const float* __restrict__ head_b, float* __restrict__ out) {
    int b = blockIdx.x, tid = threadIdx.x;
    int lane = tid & 63, wv = tid >> 6;
    __shared__ float s_pool[100];
    __shared__ float s_h2[100];
    __shared__ float s_red[2];
    if (tid < 100) {
        float a = 0.f;
#pragma unroll
        for (int sb = 0; sb < 8; ++sb) a += hp[(b * 8 + sb) * 100 + tid];
        s_pool[tid] = a * (1.f / 512.f);
    }
    __syncthreads();
    if (tid < 100) {
        float acc = fc1_b[tid];
        for (int i = 0; i < 100; ++i) acc += s_pool[i] * fc1_w[tid * 100 + i];
        s_h2[tid] = fmaxf(acc, 0.f);
    }
    __syncthreads();
    float v = (tid < 100) ? s_h2[tid] * head_w[tid] : 0.f;
#pragma unroll
    for (int off = 32; off >= 1; off >>= 1) v += __shfl_xor(v, off, 64);
    if (lane == 0) s_red[wv] = v;
    __syncthreads();
    if (tid == 0) {
        float z = s_red[0] + s_red[1] + head_b[0];
        out[b] = 1.f / (1.f + __expf(-z));
    }
}

// ---------------------------------------------------------------------------
extern "C" void kernel_launch(void* const* d_in, const int* in_sizes, int n_in,
                              void* d_out, int out_size, void* d_ws, size_t ws_size,
                              hipStream_t stream) {
    const int*   x   = (const int*)d_in[0];
    const float* u   = (const float*)d_in[1];
    const float* emb = (const float*)d_in[2];
    const float* c1w = (const float*)d_in[3];
    const float* c1b = (const float*)d_in[4];
    const float* giw = (const float*)d_in[5];
    const float* gib = (const float*)d_in[6];
    const float* c2w = (const float*)d_in[7];
    const float* c2b = (const float*)d_in[8];
    const float* liw = (const float*)d_in[9];
    const float* lib = (const float*)d_in[10];
    const float* c3w = (const float*)d_in[11];
    const float* c3b = (const float*)d_in[12];
    const float* c4w = (const float*)d_in[13];
    const float* c4b = (const float*)d_in[14];
    const float* f1w = (const float*)d_in[15];
    const float* f1b = (const float*)d_in[16];
    const float* hww = (const float*)d_in[17];
    const float* hbb = (const float*)d_in[18];
    float* out = (float*)d_out;

    char* ws = (char*)d_ws;
    short* locT   = (short*)(ws + 0);           // [512][512][112] bf16
    short* A1     = (short*)(ws + 58720256);    // 11*448*16 B each
    short* A2     = (short*)(ws + 58799104);
    short* A3     = (short*)(ws + 58877952);
    short* A4     = (short*)(ws + 58956800);    // 4*448*16 B
    float* zg     = (float*)(ws + 58985472);    // [512][112]
    float* logits = (float*)(ws + 59214848);    // [512][512]
    float* hpart  = (float*)(ws + 60263424);    // [512][8][4][112]
    float* hp     = (float*)(ws + 67603456);    // [512][8][100]

    pack_all_kernel<<<259, 64, 0, stream>>>(c1w, c2w, liw, c3w, A1, A2, A3, A4);

    size_t smemA = 2 * 72 * SSTR * 2;   // 39168 B -> 4 blocks/CU
    fused_conv_kernel<<<dim3(8, 512), 256, smemA, stream>>>(
        x, emb, A1, A2, A3, c1b, c2b, lib, locT, hpart);
    pool_gate_kernel<<<512, 128, 0, stream>>>(hpart, giw, gib, c3w, c3b, zg);
    size_t smemB = 128 * SSTR * 2;      // 34816 B -> 4 blocks/CU
    conv3_logits_kernel<<<dim3(4, 512), 256, smemB, stream>>>(
        locT, A4, zg, c4w, c4b, logits);
    sampler_kernel<<<512, 256, 0, stream>>>(u, logits, out + 512);
    head_part_kernel<<<dim3(8, 512), 256, 0, stream>>>(x, emb, out + 512, hp);
    head_fin_kernel<<<512, 128, 0, stream>>>(hp, f1w, f1b, hww, hbb, out);
}

// Round 5
// 289.156 us; speedup vs baseline: 1.8639x; 1.1440x over previous
//
#include <hip/hip_runtime.h>
#include <math.h>

#define DEV __device__ __forceinline__

typedef __attribute__((ext_vector_type(8))) short short8;
typedef __attribute__((ext_vector_type(4))) short short4v;
typedef __attribute__((ext_vector_type(4))) float f32x4;

// LDS row stride in shorts: 136 (272 B). 68 words; 68 mod 32 = 4 => 16-row
// b128 reads alias only at delta-row 8 => 2-way (free per m136).
#define SSTR 136

DEV short f2bf(float f) {
    unsigned u = __builtin_bit_cast(unsigned, f);
    unsigned r = (u + 0x7fffu + ((u >> 16) & 1u)) >> 16;
    return (short)r;
}

// ---------------------------------------------------------------------------
// Pack all four conv weights into MFMA A-fragment order (one dispatch).
// dst[((ks*7+mt)*64+lane)*8 + j] = W[f=mt*16+(lane&15)][kappa=ks*32+(lane>>4)*8+j]
// mode 0: 3-tap conv, w [100][100][3], kappa = dk*112 + c  (K = 336, padded 352)
// mode 1: conv3 loc-half, w [100][200], kappa = c (use cols 100..199), K pad 128
// ---------------------------------------------------------------------------
__global__ __launch_bounds__(64) void pack_all_kernel(
    const float* __restrict__ c1w, const float* __restrict__ c2w,
    const float* __restrict__ liw, const float* __restrict__ c3w,
    short* __restrict__ A1, short* __restrict__ A2,
    short* __restrict__ A3, short* __restrict__ A4) {
    int bx = blockIdx.x;
    const float* w; short* dst; int mode, lbx;
    if (bx < 77)       { w = c1w; dst = A1; mode = 0; lbx = bx; }
    else if (bx < 154) { w = c2w; dst = A2; mode = 0; lbx = bx - 77; }
    else if (bx < 231) { w = liw; dst = A3; mode = 0; lbx = bx - 154; }
    else               { w = c3w; dst = A4; mode = 1; lbx = bx - 231; }
    int ks = lbx / 7, mt = lbx - ks * 7;
    int lane = threadIdx.x;
    int f = mt * 16 + (lane & 15);
    int kb = ks * 32 + (lane >> 4) * 8;
    short8 v;
#pragma unroll
    for (int j = 0; j < 8; ++j) {
        int kk = kb + j;
        float val = 0.f;
        if (f < 100) {
            if (mode == 0) {
                int dk = kk / 112, c = kk - dk * 112;
                if (dk < 3 && c < 100) val = w[(f * 100 + c) * 3 + dk];
            } else {
                if (kk < 100) val = w[f * 200 + 100 + kk];
            }
        }
        v[j] = f2bf(val);
    }
    *(short8*)&dst[(lbx * 64 + lane) * 8] = v;
}

// ---------------------------------------------------------------------------
// One 3-tap conv pass, MT-SPLIT: wave wv owns mt {2wv, 2wv+1} (wave 3: just
// mt 6) and iterates ALL NT l-tiles. Per-wave global A traffic = 2 frag-rows
// x 11 ks = 22 KB (was 77 KB with nt-split) -> 4x less L2 read BW.
// B-frags come from LDS (per-CU LDS BW >> per-CU L2 share).
// Rows clamp to <=69 (clamped rows feed discarded outputs); l outside
// [0,512) zeroed (conv1d zero padding). Pad cols f>=100 write zeros (A=0).
// POOL: partial sums of relu for l in [l0,l0+64) -> hpart[pbase][112].
// TO_GLOBAL: store rows j<64 to gout.
// ---------------------------------------------------------------------------
template<int NT, bool POOL, bool TO_GLOBAL>
DEV void conv3tap(const short* __restrict__ Ap, const float* __restrict__ bias,
                  const short* s_src, short* s_dst, short* __restrict__ gout,
                  int row0l, int l0, float* __restrict__ hpart, int pbase,
                  int lane, int wv) {
    const int q = lane >> 4, n = lane & 15;
    const int mt0 = wv * 2;
    const bool two = (wv < 3);          // wave-uniform
    const f32x4 z4 = {0.f, 0.f, 0.f, 0.f};
    f32x4 acc0[NT], acc1[NT];
#pragma unroll
    for (int nt = 0; nt < NT; ++nt) { acc0[nt] = z4; acc1[nt] = z4; }
#pragma unroll
    for (int ks = 0; ks < 11; ++ks) {
        short8 a0 = *(const short8*)&Ap[(ks * 448 + mt0 * 64 + lane) * 8];
        short8 a1;
        if (two) a1 = *(const short8*)&Ap[(ks * 448 + (mt0 + 1) * 64 + lane) * 8];
        int oct = ks * 4 + q, dk, c0;
        if (oct >= 42) { dk = 0; c0 = 0; }   // zero-padded kappa; A is 0 there
        else { dk = oct / 14; c0 = (oct - dk * 14) * 8; }
#pragma unroll
        for (int nt = 0; nt < NT; ++nt) {
            int r = nt * 16 + n + dk; if (r > 69) r = 69;
            short8 bf = *(const short8*)&s_src[r * SSTR + c0];
            acc0[nt] = __builtin_amdgcn_mfma_f32_16x16x32_bf16(a0, bf, acc0[nt], 0, 0, 0);
            if (two)
                acc1[nt] = __builtin_amdgcn_mfma_f32_16x16x32_bf16(a1, bf, acc1[nt], 0, 0, 0);
        }
    }
    const int fb0 = mt0 * 16 + q * 4;
    const int fb1 = fb0 + 16;
    f32x4 bs0 = (fb0 < 100) ? *(const f32x4*)&bias[fb0] : z4;
    f32x4 bs1 = (two && fb1 < 100) ? *(const f32x4*)&bias[fb1] : z4;
    f32x4 ps0 = z4, ps1 = z4;
#pragma unroll
    for (int nt = 0; nt < NT; ++nt) {
        const int j = nt * 16 + n;
        const int l = row0l + j;
        const bool lok = (l >= 0) && (l < 512);
        const bool pok = (l >= l0) && (l < l0 + 64);
        short4v pk0, pk1;
#pragma unroll
        for (int r = 0; r < 4; ++r) {
            float v0 = fmaxf(acc0[nt][r] + bs0[r], 0.f);
            v0 = lok ? v0 : 0.f;
            pk0[r] = f2bf(v0);
            if constexpr (POOL) { if (pok) ps0[r] += v0; }
            if (two) {
                float v1 = fmaxf(acc1[nt][r] + bs1[r], 0.f);
                v1 = lok ? v1 : 0.f;
                pk1[r] = f2bf(v1);
                if constexpr (POOL) { if (pok) ps1[r] += v1; }
            }
        }
        if constexpr (TO_GLOBAL) {
            if (j < 64) {
                *(short4v*)&gout[j * 112 + fb0] = pk0;
                if (two) *(short4v*)&gout[j * 112 + fb1] = pk1;
            }
        } else {
            if (j < 70) {
                *(short4v*)&s_dst[j * SSTR + fb0] = pk0;
                if (two) *(short4v*)&s_dst[j * SSTR + fb1] = pk1;
            }
        }
    }
    if constexpr (POOL) {
#pragma unroll
        for (int off = 1; off <= 8; off <<= 1)
#pragma unroll
            for (int r = 0; r < 4; ++r) {
                ps0[r] += __shfl_xor(ps0[r], off, 64);
                ps1[r] += __shfl_xor(ps1[r], off, 64);
            }
        if (n == 0) {
            *(f32x4*)&hpart[pbase * 112 + fb0] = ps0;
            if (two) *(f32x4*)&hpart[pbase * 112 + fb1] = ps1;
        }
    }
}

// ---------------------------------------------------------------------------
// Fused conv1 -> conv2 -> li, 64-wide l-tile, 256 threads (4 waves).
// LDS 2*72*SSTR*2 = 39168 B -> 4 blocks/CU.
// s_e rows: l = l0-3+j (j=0..69). h: l = l0-2+j. c2 (alias s_e): l = l0-1+j.
// loc: l = l0+j -> global.
// ---------------------------------------------------------------------------
__global__ __launch_bounds__(256, 4) void fused_conv_kernel(
    const int* __restrict__ xidx, const float* __restrict__ emb,
    const short* __restrict__ A1, const short* __restrict__ A2,
    const short* __restrict__ A3,
    const float* __restrict__ b1, const float* __restrict__ b2,
    const float* __restrict__ b3,
    short* __restrict__ locT, float* __restrict__ hpart) {
    extern __shared__ char smem[];
    short* s_e = (short*)smem;                    // [72][SSTR], later c2
    short* s_h = (short*)(smem + 72 * SSTR * 2);  // [72][SSTR]
    const int tid = threadIdx.x;
    const int b = blockIdx.y, bx = blockIdx.x, l0 = bx * 64;
    const int lane = tid & 63, wv = tid >> 6;

    // stage e: 70 rows x 28 chunks (25 gather + 3 zero-pad cols 100..111)
#pragma unroll
    for (int idx = tid; idx < 70 * 28; idx += 256) {
        int j = idx / 28, c4 = idx - j * 28;
        int lg = l0 - 3 + j;
        short4v v = {0, 0, 0, 0};
        if (c4 < 25) {
            if (lg >= 0 && lg < 512) {
                int row = xidx[b * 512 + lg];
                f32x4 ev = *(const f32x4*)&emb[row * 100 + c4 * 4];
#pragma unroll
                for (int r = 0; r < 4; ++r) v[r] = f2bf(ev[r]);
            }
        }
        *(short4v*)&s_e[j * SSTR + c4 * 4] = v;
    }
    __syncthreads();
    // conv1: e -> h (+ pool partials over l in [l0,l0+64))
    conv3tap<5, true, false>(A1, b1, s_e, s_h, nullptr, l0 - 2, l0,
                             hpart, b * 8 + bx, lane, wv);
    __syncthreads();
    // conv2: h -> c2 (into s_e)
    conv3tap<5, false, false>(A2, b2, s_h, s_e, nullptr, l0 - 1, l0,
                              nullptr, 0, lane, wv);
    __syncthreads();
    // li: c2 -> loc (global)
    conv3tap<4, false, true>(A3, b3, s_e, nullptr,
                             locT + ((size_t)b * 512 + l0) * 112, l0, l0,
                             nullptr, 0, lane, wv);
}

// ---------------------------------------------------------------------------
// conv3 (1x1, loc half) + conv4 fused -> logits. 128-l tile; mt-split:
// wave wv owns mt {2wv, 2wv+1}, all 8 nt. Cross-wave f-reduction via LDS.
// LDS 128*SSTR*2 + 4*128*4 = 36864 B -> 4 blocks/CU.
// ---------------------------------------------------------------------------
__global__ __launch_bounds__(256, 4) void conv3_logits_kernel(
    const short* __restrict__ locT, const short* __restrict__ A4,
    const float* __restrict__ zg, const float* __restrict__ w4,
    const float* __restrict__ b4, float* __restrict__ logits) {
    extern __shared__ char smem[];
    short* s_in = (short*)smem;                       // [128][SSTR]
    float* s_part = (float*)(smem + 128 * SSTR * 2);  // [4][128]
    const int tid = threadIdx.x;
    const int b = blockIdx.y, l0r = blockIdx.x * 128;
    const int lane = tid & 63, wv = tid >> 6;
    const int q = lane >> 4, n = lane & 15;

    // stage 128 rows x 112 ch: 1792 short8 chunks, register-batched
    {
        short8 tmp[7];
#pragma unroll
        for (int p = 0; p < 7; ++p) {
            int idx = tid + p * 256;
            int j = idx / 14, c8 = idx - j * 14;
            tmp[p] = *(const short8*)&locT[((size_t)b * 512 + l0r + j) * 112 + c8 * 8];
        }
#pragma unroll
        for (int p = 0; p < 7; ++p) {
            int idx = tid + p * 256;
            int j = idx / 14, c8 = idx - j * 14;
            *(short8*)&s_in[j * SSTR + c8 * 8] = tmp[p];
        }
    }
    __syncthreads();

    const f32x4 z4 = {0.f, 0.f, 0.f, 0.f};
    const int mt0 = wv * 2;
    const bool two = (wv < 3);
    f32x4 acc0[8], acc1[8];
#pragma unroll
    for (int nt = 0; nt < 8; ++nt) { acc0[nt] = z4; acc1[nt] = z4; }
#pragma unroll
    for (int ks = 0; ks < 4; ++ks) {
        short8 a0 = *(const short8*)&A4[(ks * 448 + mt0 * 64 + lane) * 8];
        short8 a1;
        if (two) a1 = *(const short8*)&A4[(ks * 448 + (mt0 + 1) * 64 + lane) * 8];
        int c0 = (ks * 4 + q) * 8;
        if (c0 > 104) c0 = 104;   // A zero for kappa>=100
#pragma unroll
        for (int nt = 0; nt < 8; ++nt) {
            short8 bf = *(const short8*)&s_in[(nt * 16 + n) * SSTR + c0];
            acc0[nt] = __builtin_amdgcn_mfma_f32_16x16x32_bf16(a0, bf, acc0[nt], 0, 0, 0);
            if (two)
                acc1[nt] = __builtin_amdgcn_mfma_f32_16x16x32_bf16(a1, bf, acc1[nt], 0, 0, 0);
        }
    }
    const int fb0 = mt0 * 16 + q * 4, fb1 = fb0 + 16;
    f32x4 w40 = (fb0 < 100) ? *(const f32x4*)&w4[fb0] : z4;
    f32x4 w41 = (two && fb1 < 100) ? *(const f32x4*)&w4[fb1] : z4;
    f32x4 zg0 = *(const f32x4*)&zg[b * 112 + fb0];
    f32x4 zg1 = two ? *(const f32x4*)&zg[b * 112 + fb1] : z4;
#pragma unroll
    for (int nt = 0; nt < 8; ++nt) {
        float part = 0.f;
#pragma unroll
        for (int r = 0; r < 4; ++r) {
            part += fmaxf(acc0[nt][r] + zg0[r], 0.f) * w40[r];
            if (two) part += fmaxf(acc1[nt][r] + zg1[r], 0.f) * w41[r];
        }
        part += __shfl_xor(part, 16, 64);
        part += __shfl_xor(part, 32, 64);
        if (q == 0) s_part[wv * 128 + nt * 16 + n] = part;
    }
    __syncthreads();
    if (tid < 128) {
        float s = s_part[tid] + s_part[128 + tid] + s_part[256 + tid] +
                  s_part[384 + tid] + b4[0];
        logits[b * 512 + l0r + tid] = s;
    }
}

// ---------------------------------------------------------------------------
// Finish pool: hm = sum over 8 sub-block partials / 512, gate MLP, fold g:
// zg[b,f] = conv3_b[f] + sum_h g[b,h] * w3[f][h]   (f>=100 -> 0)
// ---------------------------------------------------------------------------
__global__ __launch_bounds__(128) void pool_gate_kernel(
    const float* __restrict__ hpart, const float* __restrict__ gi_w,
    const float* __restrict__ gi_b, const float* __restrict__ w3,
    const float* __restrict__ b3, float* __restrict__ zg) {
    int b = blockIdx.x, tid = threadIdx.x;
    __shared__ float s_hm[112];
    __shared__ float s_g[100];
    if (tid < 112) {
        float a = 0.f;
#pragma unroll
        for (int s = 0; s < 8; ++s) a += hpart[(b * 8 + s) * 112 + tid];
        s_hm[tid] = a * (1.f / 512.f);
    }
    __syncthreads();
    if (tid < 100) {
        float a = gi_b[tid];
        for (int f = 0; f < 100; ++f) a += s_hm[f] * gi_w[tid * 100 + f];
        s_g[tid] = fmaxf(a, 0.f);
    }
    __syncthreads();
    if (tid < 112) {
        float a = 0.f;
        if (tid < 100) {
            a = b3[tid];
            for (int h = 0; h < 100; ++h) a += s_g[h] * w3[tid * 200 + h];
        }
        zg[b * 112 + tid] = a;
    }
}

// ---------------------------------------------------------------------------
// Gumbel top-k sampler: csamples[b,l] = max_k softmax_l((gumbel+logit)/T)
// ---------------------------------------------------------------------------
__global__ __launch_bounds__(256) void sampler_kernel(
    const float* __restrict__ u, const float* __restrict__ logits,
    float* __restrict__ cs) {
    const float EPSV = 1.1920929e-07f;
    int b = blockIdx.x, tid = threadIdx.x;
    int lane = tid & 63, wv = tid >> 6;
    __shared__ float s_log[512], s_cs[512], s_red[8];
    float uu[20];
#pragma unroll
    for (int k = 0; k < 10; ++k) {
        uu[k * 2]     = u[(b * 10 + k) * 512 + tid];
        uu[k * 2 + 1] = u[(b * 10 + k) * 512 + tid + 256];
    }
    for (int l = tid; l < 512; l += 256) { s_log[l] = logits[b * 512 + l]; s_cs[l] = 0.f; }
    __syncthreads();
    for (int k = 0; k < 10; ++k) {
        float nz[2];
#pragma unroll
        for (int i = 0; i < 2; ++i) {
            int l = tid + i * 256;
            float vv = fminf(fmaxf(uu[k * 2 + i], EPSV), 1.f - EPSV);
            float g = -__logf(-__logf(vv));
            nz[i] = (g + s_log[l]) * (1.f / 0.3f);
        }
        float m = fmaxf(nz[0], nz[1]);
#pragma unroll
        for (int off = 32; off >= 1; off >>= 1) m = fmaxf(m, __shfl_xor(m, off, 64));
        if (lane == 0) s_red[wv] = m;
        __syncthreads();
        m = fmaxf(fmaxf(s_red[0], s_red[1]), fmaxf(s_red[2], s_red[3]));
        float e0 = __expf(nz[0] - m), e1 = __expf(nz[1] - m);
        float s = e0 + e1;
#pragma unroll
        for (int off = 32; off >= 1; off >>= 1) s += __shfl_xor(s, off, 64);
        if (lane == 0) s_red[4 + wv] = s;
        __syncthreads();
        float inv = 1.f / (s_red[4] + s_red[5] + s_red[6] + s_red[7]);
        s_cs[tid]       = fmaxf(s_cs[tid],       e0 * inv);
        s_cs[tid + 256] = fmaxf(s_cs[tid + 256], e1 * inv);
    }
    for (int l = tid; l < 512; l += 256) cs[b * 512 + l] = s_cs[l];
}

// ---------------------------------------------------------------------------
// Distil head, phase 1: partial pooled sums over a 64-long l-slice.
// ---------------------------------------------------------------------------
__global__ __launch_bounds__(256) void head_part_kernel(
    const int* __restrict__ xidx, const float* __restrict__ emb,
    const float* __restrict__ cs, float* __restrict__ hp) {
    int sb = blockIdx.x, b = blockIdx.y;
    int tid = threadIdx.x;
    __shared__ int s_x[64];
    __shared__ float s_c[64];
    __shared__ float s_acc[8][104];
    if (tid < 64) {
        int l = sb * 64 + tid;
        s_x[tid] = xidx[b * 512 + l];
        s_c[tid] = cs[b * 512 + l];
    }
    __syncthreads();
    int s = tid & 31, lq = tid >> 5;
    if (s < 25) {
        f32x4 a = {0.f, 0.f, 0.f, 0.f};
#pragma unroll
        for (int i = 0; i < 8; ++i) {
            int ll = lq * 8 + i;
            int row = s_x[ll];
            float cv = s_c[ll];
            f32x4 ev = *(const f32x4*)&emb[row * 100 + s * 4];
#pragma unroll
            for (int r = 0; r < 4; ++r) a[r] += ev[r] * cv;
        }
        *(f32x4*)&s_acc[lq][s * 4] = a;
    }
    __syncthreads();
    if (tid < 100) {
        float v = 0.f;
#pragma unroll
        for (int j = 0; j < 8; ++j) v += s_acc[j][tid];
        hp[(b * 8 + sb) * 100 + tid] = v;
    }
}

// ---------------------------------------------------------------------------
// Distil head, phase 2: pooled -> fc1 relu -> sigmoid head
// ---------------------------------------------------------------------------
__global__ __launch_bounds__(128) void head_fin_kernel(
    const float* __restrict__ hp, const float* __restrict__ fc1_w,
    const float* __restrict__ fc1_b, const float* __restrict__ head_w,
    const float* __restrict__ head_b, float* __restrict__ out) {
    int b = blockIdx.x, tid = threadIdx.x;
    int lane = tid & 63, wv = tid >> 6;
    __shared__ float s_pool[100];
    __shared__ float s_h2[100];
    __shared__ float s_red[2];
    if (tid < 100) {
        float a = 0.f;
#pragma unroll
        for (int sb = 0; sb < 8; ++sb) a += hp[(b * 8 + sb) * 100 + tid];
        s_pool[tid] = a * (1.f / 512.f);
    }
    __syncthreads();
    if (tid < 100) {
        float acc = fc1_b[tid];
        for (int i = 0; i < 100; ++i) acc += s_pool[i] * fc1_w[tid * 100 + i];
        s_h2[tid] = fmaxf(acc, 0.f);
    }
    __syncthreads();
    float v = (tid < 100) ? s_h2[tid] * head_w[tid] : 0.f;
#pragma unroll
    for (int off = 32; off >= 1; off >>= 1) v += __shfl_xor(v, off, 64);
    if (lane == 0) s_red[wv] = v;
    __syncthreads();
    if (tid == 0) {
        float z = s_red[0] + s_red[1] + head_b[0];
        out[b] = 1.f / (1.f + __expf(-z));
    }
}

// ---------------------------------------------------------------------------
extern "C" void kernel_launch(void* const* d_in, const int* in_sizes, int n_in,
                              void* d_out, int out_size, void* d_ws, size_t ws_size,
                              hipStream_t stream) {
    const int*   x   = (const int*)d_in[0];
    const float* u   = (const float*)d_in[1];
    const float* emb = (const float*)d_in[2];
    const float* c1w = (const float*)d_in[3];
    const float* c1b = (const float*)d_in[4];
    const float* giw = (const float*)d_in[5];
    const float* gib = (const float*)d_in[6];
    const float* c2w = (const float*)d_in[7];
    const float* c2b = (const float*)d_in[8];
    const float* liw = (const float*)d_in[9];
    const float* lib = (const float*)d_in[10];
    const float* c3w = (const float*)d_in[11];
    const float* c3b = (const float*)d_in[12];
    const float* c4w = (const float*)d_in[13];
    const float* c4b = (const float*)d_in[14];
    const float* f1w = (const float*)d_in[15];
    const float* f1b = (const float*)d_in[16];
    const float* hww = (const float*)d_in[17];
    const float* hbb = (const float*)d_in[18];
    float* out = (float*)d_out;

    char* ws = (char*)d_ws;
    short* locT   = (short*)(ws + 0);           // [512][512][112] bf16
    short* A1     = (short*)(ws + 58720256);    // 11*448*16 B each
    short* A2     = (short*)(ws + 58799104);
    short* A3     = (short*)(ws + 58877952);
    short* A4     = (short*)(ws + 58956800);    // 4*448*16 B
    float* zg     = (float*)(ws + 58985472);    // [512][112]
    float* logits = (float*)(ws + 59214848);    // [512][512]
    float* hpart  = (float*)(ws + 60263424);    // [512][8][112]
    float* hp     = (float*)(ws + 62098432);    // [512][8][100]

    pack_all_kernel<<<259, 64, 0, stream>>>(c1w, c2w, liw, c3w, A1, A2, A3, A4);

    size_t smemA = 2 * 72 * SSTR * 2;             // 39168 B -> 4 blocks/CU
    fused_conv_kernel<<<dim3(8, 512), 256, smemA, stream>>>(
        x, emb, A1, A2, A3, c1b, c2b, lib, locT, hpart);
    pool_gate_kernel<<<512, 128, 0, stream>>>(hpart, giw, gib, c3w, c3b, zg);
    size_t smemB = 128 * SSTR * 2 + 4 * 128 * 4;  // 36864 B -> 4 blocks/CU
    conv3_logits_kernel<<<dim3(4, 512), 256, smemB, stream>>>(
        locT, A4, zg, c4w, c4b, logits);
    sampler_kernel<<<512, 256, 0, stream>>>(u, logits, out + 512);
    head_part_kernel<<<dim3(8, 512), 256, 0, stream>>>(x, emb, out + 512, hp);
    head_fin_kernel<<<512, 128, 0, stream>>>(hp, f1w, f1b, hww, hbb, out);
}

// Round 6
// 288.109 us; speedup vs baseline: 1.8707x; 1.0036x over previous
//
#include <hip/hip_runtime.h>
#include <math.h>

#define DEV __device__ __forceinline__

typedef __attribute__((ext_vector_type(8))) short short8;
typedef __attribute__((ext_vector_type(4))) short short4v;
typedef __attribute__((ext_vector_type(4))) float f32x4;

// LDS row stride in shorts (272 B = 68 words; 68 mod 32 = 4 -> b128 reads
// land 2-way on banks = free per m136).
#define SSTR 136

DEV short f2bf(float f) {
    unsigned u = __builtin_bit_cast(unsigned, f);
    unsigned r = (u + 0x7fffu + ((u >> 16) & 1u)) >> 16;
    return (short)r;
}

// ---------------------------------------------------------------------------
// emb f32 [V][100] -> bf16 [V][112], cols 100..111 zeroed. 8 rows/block.
// ---------------------------------------------------------------------------
__global__ __launch_bounds__(256) void emb_cvt_kernel(
    const float* __restrict__ emb, short* __restrict__ embT) {
    int t = threadIdx.x;
    int row = blockIdx.x * 8 + (t >> 5);
    int c4 = t & 31;
    if (c4 >= 28) return;
    short4v v = {0, 0, 0, 0};
    if (c4 < 25) {
        f32x4 e = *(const f32x4*)&emb[row * 100 + c4 * 4];
#pragma unroll
        for (int r = 0; r < 4; ++r) v[r] = f2bf(e[r]);
    }
    *(short4v*)&embT[row * 112 + c4 * 4] = v;
}

// ---------------------------------------------------------------------------
// Pack conv weights into MFMA A-fragment order.
// mode 0 (3-tap): 13 octets per tap -> kappa: oct=kk>>3, dk=oct/13,
//   c=(oct-13*dk)*8+(kk&7); K = 320 (10 ks), oct 39 zero.
// mode 1 (conv3 loc half): kappa = c (cols 100..199 of w[100][200]), K 128.
// dst[((ks*7+mt)*64+lane)*8+j] = W[f=mt*16+(lane&15)][kappa=ks*32+(lane>>4)*8+j]
// ---------------------------------------------------------------------------
__global__ __launch_bounds__(64) void pack_all_kernel(
    const float* __restrict__ c1w, const float* __restrict__ c2w,
    const float* __restrict__ liw, const float* __restrict__ c3w,
    short* __restrict__ A1, short* __restrict__ A2,
    short* __restrict__ A3, short* __restrict__ A4) {
    int bx = blockIdx.x;
    const float* w; short* dst; int mode, lbx;
    if (bx < 70)       { w = c1w; dst = A1; mode = 0; lbx = bx; }
    else if (bx < 140) { w = c2w; dst = A2; mode = 0; lbx = bx - 70; }
    else if (bx < 210) { w = liw; dst = A3; mode = 0; lbx = bx - 140; }
    else               { w = c3w; dst = A4; mode = 1; lbx = bx - 210; }
    int lane = threadIdx.x;
    int f = lbx % 7 * 16 + (lane & 15);
    int kb = (lbx / 7) * 32 + (lane >> 4) * 8;
    short8 v;
#pragma unroll
    for (int j = 0; j < 8; ++j) {
        int kk = kb + j;
        float val = 0.f;
        if (f < 100) {
            if (mode == 0) {
                int oct = kk >> 3, dk = oct / 13;
                int c = (oct - 13 * dk) * 8 + (kk & 7);
                if (dk < 3 && c < 100) val = w[(f * 100 + c) * 3 + dk];
            } else {
                if (kk < 100) val = w[f * 200 + 100 + kk];
            }
        }
        v[j] = f2bf(val);
    }
    *(short8*)&dst[(lbx * 64 + lane) * 8] = v;
}

// ---------------------------------------------------------------------------
// One 3-tap conv pass, mt-split (wave wv owns mt {2wv,2wv+1}; wave 3 one mt).
// 10 k-steps (13 octets/tap packing): dk = oct/13, c0 = (oct-13*dk)*8.
// nt 0..3 read via ONE base vaddr + DS imm offsets (nt*4352 B); only nt 4
// computes a clamped address. Needed output rows never touch clamped/garbage
// rows (halo chain: loc<=63 -> c2<=65 -> h<=67 -> e<=69, all staged).
// POOL: relu partial sums for l in [l0,l0+64) -> hpart[pbase][112].
// TO_GLOBAL: store rows j<64 to gout.
// ---------------------------------------------------------------------------
template<int NT, bool POOL, bool TO_GLOBAL>
DEV void conv3tap(const short* __restrict__ Ap, const float* __restrict__ bias,
                  const short* s_src, short* s_dst, short* __restrict__ gout,
                  int row0l, int l0, float* __restrict__ hpart, int pbase,
                  int lane, int wv) {
    const int q = lane >> 4, n = lane & 15;
    const int mt0 = wv * 2;
    const bool two = (wv < 3);          // wave-uniform
    const f32x4 z4 = {0.f, 0.f, 0.f, 0.f};
    f32x4 acc0[NT], acc1[NT];
#pragma unroll
    for (int nt = 0; nt < NT; ++nt) { acc0[nt] = z4; acc1[nt] = z4; }
#pragma unroll
    for (int ks = 0; ks < 10; ++ks) {
        short8 a0 = *(const short8*)&Ap[(ks * 448 + mt0 * 64 + lane) * 8];
        short8 a1;
        if (two) a1 = *(const short8*)&Ap[(ks * 448 + (mt0 + 1) * 64 + lane) * 8];
        int oct = ks * 4 + q;
        int dk = oct / 13;                     // 0..3 (3 only at oct 39, A=0)
        int c0 = (oct - 13 * dk) * 8;
        const short* bptr = s_src + (n + dk) * SSTR + c0;
#pragma unroll
        for (int nt = 0; nt < NT; ++nt) {
            short8 bf;
            if (nt < 4) {
                bf = *(const short8*)(bptr + nt * 16 * SSTR);   // DS imm offset
            } else {
                int r = 64 + n + dk; if (r > 69) r = 69;        // discarded rows only
                bf = *(const short8*)&s_src[r * SSTR + c0];
            }
            acc0[nt] = __builtin_amdgcn_mfma_f32_16x16x32_bf16(a0, bf, acc0[nt], 0, 0, 0);
            if (two)
                acc1[nt] = __builtin_amdgcn_mfma_f32_16x16x32_bf16(a1, bf, acc1[nt], 0, 0, 0);
        }
    }
    const int fb0 = mt0 * 16 + q * 4;
    const int fb1 = fb0 + 16;
    f32x4 bs0 = (fb0 < 100) ? *(const f32x4*)&bias[fb0] : z4;
    f32x4 bs1 = (two && fb1 < 100) ? *(const f32x4*)&bias[fb1] : z4;
    f32x4 ps0 = z4, ps1 = z4;
#pragma unroll
    for (int nt = 0; nt < NT; ++nt) {
        const int j = nt * 16 + n;
        const int l = row0l + j;
        const bool lok = (l >= 0) && (l < 512);
        const bool pok = (l >= l0) && (l < l0 + 64);
        short4v pk0, pk1;
#pragma unroll
        for (int r = 0; r < 4; ++r) {
            float v0 = fmaxf(acc0[nt][r] + bs0[r], 0.f);
            v0 = lok ? v0 : 0.f;
            pk0[r] = f2bf(v0);
            if constexpr (POOL) { if (pok) ps0[r] += v0; }
            if (two) {
                float v1 = fmaxf(acc1[nt][r] + bs1[r], 0.f);
                v1 = lok ? v1 : 0.f;
                pk1[r] = f2bf(v1);
                if constexpr (POOL) { if (pok) ps1[r] += v1; }
            }
        }
        if constexpr (TO_GLOBAL) {
            if (j < 64) {
                *(short4v*)&gout[j * 112 + fb0] = pk0;
                if (two) *(short4v*)&gout[j * 112 + fb1] = pk1;
            }
        } else {
            if (j < 70) {
                *(short4v*)&s_dst[j * SSTR + fb0] = pk0;
                if (two) *(short4v*)&s_dst[j * SSTR + fb1] = pk1;
            }
        }
    }
    if constexpr (POOL) {
#pragma unroll
        for (int off = 1; off <= 8; off <<= 1)
#pragma unroll
            for (int r = 0; r < 4; ++r) {
                ps0[r] += __shfl_xor(ps0[r], off, 64);
                ps1[r] += __shfl_xor(ps1[r], off, 64);
            }
        if (n == 0) {
            *(f32x4*)&hpart[pbase * 112 + fb0] = ps0;
            if (two) *(f32x4*)&hpart[pbase * 112 + fb1] = ps1;
        }
    }
}

// ---------------------------------------------------------------------------
// Fused conv1 -> conv2 -> li, 64-wide l-tile, 256 threads (4 waves).
// LDS 2*72*SSTR*2 = 39168 B -> 4 blocks/CU. Staging copies bf16 embT rows
// (no f32->bf16 conversion, shift/mask indexing, b128 both sides).
// ---------------------------------------------------------------------------
__global__ __launch_bounds__(256, 4) void fused_conv_kernel(
    const int* __restrict__ xidx, const short* __restrict__ embT,
    const short* __restrict__ A1, const short* __restrict__ A2,
    const short* __restrict__ A3,
    const float* __restrict__ b1, const float* __restrict__ b2,
    const float* __restrict__ b3,
    short* __restrict__ locT, float* __restrict__ hpart) {
    extern __shared__ char smem[];
    short* s_e = (short*)smem;                    // [72][SSTR], later c2
    short* s_h = (short*)(smem + 72 * SSTR * 2);  // [72][SSTR]
    const int tid = threadIdx.x;
    const int b = blockIdx.y, bx = blockIdx.x, l0 = bx * 64;
    const int lane = tid & 63, wv = tid >> 6;

    // stage e: 70 rows x 14 b128 chunks (virtual 16-grid; c8>=14 skipped)
#pragma unroll
    for (int p = 0; p < 5; ++p) {
        int idx = tid + p * 256;           // 0..1279, need j<70
        int j = idx >> 4, c8 = idx & 15;
        if (j < 70 && c8 < 14) {
            int lg = l0 - 3 + j;
            short8 v = {0, 0, 0, 0, 0, 0, 0, 0};
            if (lg >= 0 && lg < 512) {
                int row = xidx[b * 512 + lg];
                v = *(const short8*)&embT[row * 112 + c8 * 8];
            }
            *(short8*)&s_e[j * SSTR + c8 * 8] = v;
        }
    }
    __syncthreads();
    // conv1: e -> h (+ pool partials over l in [l0,l0+64))
    conv3tap<5, true, false>(A1, b1, s_e, s_h, nullptr, l0 - 2, l0,
                             hpart, b * 8 + bx, lane, wv);
    __syncthreads();
    // conv2: h -> c2 (into s_e)
    conv3tap<5, false, false>(A2, b2, s_h, s_e, nullptr, l0 - 1, l0,
                              nullptr, 0, lane, wv);
    __syncthreads();
    // li: c2 -> loc (global)
    conv3tap<4, false, true>(A3, b3, s_e, nullptr,
                             locT + ((size_t)b * 512 + l0) * 112, l0, l0,
                             nullptr, 0, lane, wv);
}

// ---------------------------------------------------------------------------
// conv3 (1x1, loc half) + conv4 fused -> logits. 128-l tile; mt-split;
// all 8 nt reads off one base vaddr via DS imm offsets (nt*4352 B).
// LDS 128*SSTR*2 + 4*128*4 = 36864 B -> 4 blocks/CU.
// ---------------------------------------------------------------------------
__global__ __launch_bounds__(256, 4) void conv3_logits_kernel(
    const short* __restrict__ locT, const short* __restrict__ A4,
    const float* __restrict__ zg, const float* __restrict__ w4,
    const float* __restrict__ b4, float* __restrict__ logits) {
    extern __shared__ char smem[];
    short* s_in = (short*)smem;                       // [128][SSTR]
    float* s_part = (float*)(smem + 128 * SSTR * 2);  // [4][128]
    const int tid = threadIdx.x;
    const int b = blockIdx.y, l0r = blockIdx.x * 128;
    const int lane = tid & 63, wv = tid >> 6;
    const int q = lane >> 4, n = lane & 15;

    // stage 128 rows x 14 b128 chunks (virtual 16-grid), register-batched
    {
        short8 tmp[8];
#pragma unroll
        for (int p = 0; p < 8; ++p) {
            int idx = tid + p * 256;
            int j = idx >> 4, c8 = idx & 15;
            if (c8 < 14)
                tmp[p] = *(const short8*)&locT[((size_t)b * 512 + l0r + j) * 112 + c8 * 8];
        }
#pragma unroll
        for (int p = 0; p < 8; ++p) {
            int idx = tid + p * 256;
            int j = idx >> 4, c8 = idx & 15;
            if (c8 < 14)
                *(short8*)&s_in[j * SSTR + c8 * 8] = tmp[p];
        }
    }
    __syncthreads();

    const f32x4 z4 = {0.f, 0.f, 0.f, 0.f};
    const int mt0 = wv * 2;
    const bool two = (wv < 3);
    f32x4 acc0[8], acc1[8];
#pragma unroll
    for (int nt = 0; nt < 8; ++nt) { acc0[nt] = z4; acc1[nt] = z4; }
#pragma unroll
    for (int ks = 0; ks < 4; ++ks) {
        short8 a0 = *(const short8*)&A4[(ks * 448 + mt0 * 64 + lane) * 8];
        short8 a1;
        if (two) a1 = *(const short8*)&A4[(ks * 448 + (mt0 + 1) * 64 + lane) * 8];
        int c0 = (ks * 4 + q) * 8;
        if (c0 > 104) c0 = 104;   // A zero for kappa>=100; col 104..111 zero
        const short* bptr = s_in + n * SSTR + c0;
#pragma unroll
        for (int nt = 0; nt < 8; ++nt) {
            short8 bf = *(const short8*)(bptr + nt * 16 * SSTR);  // DS imm
            acc0[nt] = __builtin_amdgcn_mfma_f32_16x16x32_bf16(a0, bf, acc0[nt], 0, 0, 0);
            if (two)
                acc1[nt] = __builtin_amdgcn_mfma_f32_16x16x32_bf16(a1, bf, acc1[nt], 0, 0, 0);
        }
    }
    const int fb0 = mt0 * 16 + q * 4, fb1 = fb0 + 16;
    f32x4 w40 = (fb0 < 100) ? *(const f32x4*)&w4[fb0] : z4;
    f32x4 w41 = (two && fb1 < 100) ? *(const f32x4*)&w4[fb1] : z4;
    f32x4 zg0 = *(const f32x4*)&zg[b * 112 + fb0];
    f32x4 zg1 = two ? *(const f32x4*)&zg[b * 112 + fb1] : z4;
#pragma unroll
    for (int nt = 0; nt < 8; ++nt) {
        float part = 0.f;
#pragma unroll
        for (int r = 0; r < 4; ++r) {
            part += fmaxf(acc0[nt][r] + zg0[r], 0.f) * w40[r];
            if (two) part += fmaxf(acc1[nt][r] + zg1[r], 0.f) * w41[r];
        }
        part += __shfl_xor(part, 16, 64);
        part += __shfl_xor(part, 32, 64);
        if (q == 0) s_part[wv * 128 + nt * 16 + n] = part;
    }
    __syncthreads();
    if (tid < 128) {
        float s = s_part[tid] + s_part[128 + tid] + s_part[256 + tid] +
                  s_part[384 + tid] + b4[0];
        logits[b * 512 + l0r + tid] = s;
    }
}

// ---------------------------------------------------------------------------
// Finish pool: hm = sum over 8 sub-block partials / 512, gate MLP, fold g:
// zg[b,f] = conv3_b[f] + sum_h g[b,h] * w3[f][h]   (f>=100 -> 0)
// ---------------------------------------------------------------------------
__global__ __launch_bounds__(128) void pool_gate_kernel(
    const float* __restrict__ hpart, const float* __restrict__ gi_w,
    const float* __restrict__ gi_b, const float* __restrict__ w3,
    const float* __restrict__ b3, float* __restrict__ zg) {
    int b = blockIdx.x, tid = threadIdx.x;
    __shared__ float s_hm[112];
    __shared__ float s_g[100];
    if (tid < 112) {
        float a = 0.f;
#pragma unroll
        for (int s = 0; s < 8; ++s) a += hpart[(b * 8 + s) * 112 + tid];
        s_hm[tid] = a * (1.f / 512.f);
    }
    __syncthreads();
    if (tid < 100) {
        float a = gi_b[tid];
        for (int f = 0; f < 100; ++f) a += s_hm[f] * gi_w[tid * 100 + f];
        s_g[tid] = fmaxf(a, 0.f);
    }
    __syncthreads();
    if (tid < 112) {
        float a = 0.f;
        if (tid < 100) {
            a = b3[tid];
            for (int h = 0; h < 100; ++h) a += s_g[h] * w3[tid * 200 + h];
        }
        zg[b * 112 + tid] = a;
    }
}

// ---------------------------------------------------------------------------
// Gumbel top-k sampler: csamples[b,l] = max_k softmax_l((gumbel+logit)/T)
// ---------------------------------------------------------------------------
__global__ __launch_bounds__(256) void sampler_kernel(
    const float* __restrict__ u, const float* __restrict__ logits,
    float* __restrict__ cs) {
    const float EPSV = 1.1920929e-07f;
    int b = blockIdx.x, tid = threadIdx.x;
    int lane = tid & 63, wv = tid >> 6;
    __shared__ float s_log[512], s_cs[512], s_red[8];
    float uu[20];
#pragma unroll
    for (int k = 0; k < 10; ++k) {
        uu[k * 2]     = u[(b * 10 + k) * 512 + tid];
        uu[k * 2 + 1] = u[(b * 10 + k) * 512 + tid + 256];
    }
    for (int l = tid; l < 512; l += 256) { s_log[l] = logits[b * 512 + l]; s_cs[l] = 0.f; }
    __syncthreads();
    for (int k = 0; k < 10; ++k) {
        float nz[2];
#pragma unroll
        for (int i = 0; i < 2; ++i) {
            int l = tid + i * 256;
            float vv = fminf(fmaxf(uu[k * 2 + i], EPSV), 1.f - EPSV);
            float g = -__logf(-__logf(vv));
            nz[i] = (g + s_log[l]) * (1.f / 0.3f);
        }
        float m = fmaxf(nz[0], nz[1]);
#pragma unroll
        for (int off = 32; off >= 1; off >>= 1) m = fmaxf(m, __shfl_xor(m, off, 64));
        if (lane == 0) s_red[wv] = m;
        __syncthreads();
        m = fmaxf(fmaxf(s_red[0], s_red[1]), fmaxf(s_red[2], s_red[3]));
        float e0 = __expf(nz[0] - m), e1 = __expf(nz[1] - m);
        float s = e0 + e1;
#pragma unroll
        for (int off = 32; off >= 1; off >>= 1) s += __shfl_xor(s, off, 64);
        if (lane == 0) s_red[4 + wv] = s;
        __syncthreads();
        float inv = 1.f / (s_red[4] + s_red[5] + s_red[6] + s_red[7]);
        s_cs[tid]       = fmaxf(s_cs[tid],       e0 * inv);
        s_cs[tid + 256] = fmaxf(s_cs[tid + 256], e1 * inv);
    }
    for (int l = tid; l < 512; l += 256) cs[b * 512 + l] = s_cs[l];
}

// ---------------------------------------------------------------------------
// Distil head, phase 1: partial pooled sums over a 64-long l-slice.
// ---------------------------------------------------------------------------
__global__ __launch_bounds__(256) void head_part_kernel(
    const int* __restrict__ xidx, const float* __restrict__ emb,
    const float* __restrict__ cs, float* __restrict__ hp) {
    int sb = blockIdx.x, b = blockIdx.y;
    int tid = threadIdx.x;
    __shared__ int s_x[64];
    __shared__ float s_c[64];
    __shared__ float s_acc[8][104];
    if (tid < 64) {
        int l = sb * 64 + tid;
        s_x[tid] = xidx[b * 512 + l];
        s_c[tid] = cs[b * 512 + l];
    }
    __syncthreads();
    int s = tid & 31, lq = tid >> 5;
    if (s < 25) {
        f32x4 a = {0.f, 0.f, 0.f, 0.f};
#pragma unroll
        for (int i = 0; i < 8; ++i) {
            int ll = lq * 8 + i;
            int row = s_x[ll];
            float cv = s_c[ll];
            f32x4 ev = *(const f32x4*)&emb[row * 100 + s * 4];
#pragma unroll
            for (int r = 0; r < 4; ++r) a[r] += ev[r] * cv;
        }
        *(f32x4*)&s_acc[lq][s * 4] = a;
    }
    __syncthreads();
    if (tid < 100) {
        float v = 0.f;
#pragma unroll
        for (int j = 0; j < 8; ++j) v += s_acc[j][tid];
        hp[(b * 8 + sb) * 100 + tid] = v;
    }
}

// ---------------------------------------------------------------------------
// Distil head, phase 2: pooled -> fc1 relu -> sigmoid head
// ---------------------------------------------------------------------------
__global__ __launch_bounds__(128) void head_fin_kernel(
    const float* __restrict__ hp, const float* __restrict__ fc1_w,
    const float* __restrict__ fc1_b, const float* __restrict__ head_w,
    const float* __restrict__ head_b, float* __restrict__ out) {
    int b = blockIdx.x, tid = threadIdx.x;
    int lane = tid & 63, wv = tid >> 6;
    __shared__ float s_pool[100];
    __shared__ float s_h2[100];
    __shared__ float s_red[2];
    if (tid < 100) {
        float a = 0.f;
#pragma unroll
        for (int sb = 0; sb < 8; ++sb) a += hp[(b * 8 + sb) * 100 + tid];
        s_pool[tid] = a * (1.f / 512.f);
    }
    __syncthreads();
    if (tid < 100) {
        float acc = fc1_b[tid];
        for (int i = 0; i < 100; ++i) acc += s_pool[i] * fc1_w[tid * 100 + i];
        s_h2[tid] = fmaxf(acc, 0.f);
    }
    __syncthreads();
    float v = (tid < 100) ? s_h2[tid] * head_w[tid] : 0.f;
#pragma unroll
    for (int off = 32; off >= 1; off >>= 1) v += __shfl_xor(v, off, 64);
    if (lane == 0) s_red[wv] = v;
    __syncthreads();
    if (tid == 0) {
        float z = s_red[0] + s_red[1] + head_b[0];
        out[b] = 1.f / (1.f + __expf(-z));
    }
}

// ---------------------------------------------------------------------------
extern "C" void kernel_launch(void* const* d_in, const int* in_sizes, int n_in,
                              void* d_out, int out_size, void* d_ws, size_t ws_size,
                              hipStream_t stream) {
    const int*   x   = (const int*)d_in[0];
    const float* u   = (const float*)d_in[1];
    const float* emb = (const float*)d_in[2];
    const float* c1w = (const float*)d_in[3];
    const float* c1b = (const float*)d_in[4];
    const float* giw = (const float*)d_in[5];
    const float* gib = (const float*)d_in[6];
    const float* c2w = (const float*)d_in[7];
    const float* c2b = (const float*)d_in[8];
    const float* liw = (const float*)d_in[9];
    const float* lib = (const float*)d_in[10];
    const float* c3w = (const float*)d_in[11];
    const float* c3b = (const float*)d_in[12];
    const float* c4w = (const float*)d_in[13];
    const float* c4b = (const float*)d_in[14];
    const float* f1w = (const float*)d_in[15];
    const float* f1b = (const float*)d_in[16];
    const float* hww = (const float*)d_in[17];
    const float* hbb = (const float*)d_in[18];
    float* out = (float*)d_out;

    char* ws = (char*)d_ws;
    short* locT   = (short*)(ws + 0);           // [512][512][112] bf16 (58.7 MB)
    short* embT   = (short*)(ws + 58720256);    // [100000][112] bf16 (22.4 MB)
    short* A1     = (short*)(ws + 81120256);    // 10*448*16 B each
    short* A2     = (short*)(ws + 81191936);
    short* A3     = (short*)(ws + 81263616);
    short* A4     = (short*)(ws + 81335296);    // 4*448*16 B
    float* zg     = (float*)(ws + 81363968);    // [512][112]
    float* logits = (float*)(ws + 81593344);    // [512][512]
    float* hpart  = (float*)(ws + 82641920);    // [512][8][112]
    float* hp     = (float*)(ws + 84476928);    // [512][8][100]

    emb_cvt_kernel<<<12500, 256, 0, stream>>>(emb, embT);
    pack_all_kernel<<<238, 64, 0, stream>>>(c1w, c2w, liw, c3w, A1, A2, A3, A4);

    size_t smemA = 2 * 72 * SSTR * 2;             // 39168 B -> 4 blocks/CU
    fused_conv_kernel<<<dim3(8, 512), 256, smemA, stream>>>(
        x, embT, A1, A2, A3, c1b, c2b, lib, locT, hpart);
    pool_gate_kernel<<<512, 128, 0, stream>>>(hpart, giw, gib, c3w, c3b, zg);
    size_t smemB = 128 * SSTR * 2 + 4 * 128 * 4;  // 36864 B -> 4 blocks/CU
    conv3_logits_kernel<<<dim3(4, 512), 256, smemB, stream>>>(
        locT, A4, zg, c4w, c4b, logits);
    sampler_kernel<<<512, 256, 0, stream>>>(u, logits, out + 512);
    head_part_kernel<<<dim3(8, 512), 256, 0, stream>>>(x, emb, out + 512, hp);
    head_fin_kernel<<<512, 128, 0, stream>>>(hp, f1w, f1b, hww, hbb, out);
}

// Round 7
// 277.175 us; speedup vs baseline: 1.9445x; 1.0394x over previous
//
#include <hip/hip_runtime.h>
#include <math.h>

#define DEV __device__ __forceinline__

typedef __attribute__((ext_vector_type(8))) short short8;
typedef __attribute__((ext_vector_type(4))) short short4v;
typedef __attribute__((ext_vector_type(4))) float f32x4;
typedef __attribute__((ext_vector_type(2))) unsigned uint2v;

// LDS row stride in shorts (272 B = 68 words; 68 mod 32 = 4 -> b128 reads
// land 2-way on banks = free per m136).
#define SSTR 136

DEV short f2bf(float f) {
    unsigned u = __builtin_bit_cast(unsigned, f);
    unsigned r = (u + 0x7fffu + ((u >> 16) & 1u)) >> 16;
    return (short)r;
}

#if __has_builtin(__builtin_amdgcn_cvt_pk_bf16_f32)
DEV unsigned pk2bf(float a, float b) {
    auto v = __builtin_amdgcn_cvt_pk_bf16_f32(a, b);
    return __builtin_bit_cast(unsigned, v);
}
#else
DEV unsigned pk2bf(float a, float b) {
    return ((unsigned)(unsigned short)f2bf(a)) |
           (((unsigned)(unsigned short)f2bf(b)) << 16);
}
#endif

DEV float bfu(short s) {
    unsigned u = ((unsigned)(unsigned short)s) << 16;
    return __builtin_bit_cast(float, u);
}

// ---------------------------------------------------------------------------
// emb f32 [V][100] -> bf16 [V][112], cols 100..111 zeroed. 8 rows/block.
// ---------------------------------------------------------------------------
__global__ __launch_bounds__(256) void emb_cvt_kernel(
    const float* __restrict__ emb, short* __restrict__ embT) {
    int t = threadIdx.x;
    int row = blockIdx.x * 8 + (t >> 5);
    int c4 = t & 31;
    if (c4 >= 28) return;
    short4v v = {0, 0, 0, 0};
    if (c4 < 25) {
        f32x4 e = *(const f32x4*)&emb[row * 100 + c4 * 4];
#pragma unroll
        for (int r = 0; r < 4; ++r) v[r] = f2bf(e[r]);
    }
    *(short4v*)&embT[row * 112 + c4 * 4] = v;
}

// ---------------------------------------------------------------------------
// Pack conv weights into MFMA A-fragment order.
// mode 0 (3-tap): 13 octets per tap -> kappa: oct=kk>>3, dk=oct/13,
//   c=(oct-13*dk)*8+(kk&7); K = 320 (10 ks), oct 39 zero.
// mode 1 (conv3 loc half): kappa = c (cols 100..199 of w[100][200]), K 128.
// ---------------------------------------------------------------------------
__global__ __launch_bounds__(64) void pack_all_kernel(
    const float* __restrict__ c1w, const float* __restrict__ c2w,
    const float* __restrict__ liw, const float* __restrict__ c3w,
    short* __restrict__ A1, short* __restrict__ A2,
    short* __restrict__ A3, short* __restrict__ A4) {
    int bx = blockIdx.x;
    const float* w; short* dst; int mode, lbx;
    if (bx < 70)       { w = c1w; dst = A1; mode = 0; lbx = bx; }
    else if (bx < 140) { w = c2w; dst = A2; mode = 0; lbx = bx - 70; }
    else if (bx < 210) { w = liw; dst = A3; mode = 0; lbx = bx - 140; }
    else               { w = c3w; dst = A4; mode = 1; lbx = bx - 210; }
    int lane = threadIdx.x;
    int f = lbx % 7 * 16 + (lane & 15);
    int kb = (lbx / 7) * 32 + (lane >> 4) * 8;
    short8 v;
#pragma unroll
    for (int j = 0; j < 8; ++j) {
        int kk = kb + j;
        float val = 0.f;
        if (f < 100) {
            if (mode == 0) {
                int oct = kk >> 3, dk = oct / 13;
                int c = (oct - 13 * dk) * 8 + (kk & 7);
                if (dk < 3 && c < 100) val = w[(f * 100 + c) * 3 + dk];
            } else {
                if (kk < 100) val = w[f * 200 + 100 + kk];
            }
        }
        v[j] = f2bf(val);
    }
    *(short8*)&dst[(lbx * 64 + lane) * 8] = v;
}

// ---------------------------------------------------------------------------
// One 3-tap conv pass, mt-split. Accumulator initialized with the BIAS
// (D=A*B+C -> bias add free). B-offsets precomputed per-lane in bofs[10]
// (byte offsets); nt 0..3 share a vaddr via DS imm offsets, nt 4 uses the
// clamped bofs4. EDGE template: only edge blocks (bx 0/7) pay the l-range
// zeroing cndmask. Pad channels f>=100 have bias 0 and A rows 0 -> stay 0.
// ---------------------------------------------------------------------------
template<int NT, bool POOL, bool TO_GLOBAL, bool EDGE>
DEV void conv3tap(const short* __restrict__ Ap, const short* s_src,
                  short* s_dst, short* __restrict__ gout,
                  const int* bofs, const int* bofs4,
                  const f32x4 bs0, const f32x4 bs1,
                  int row0l, int l0, float* __restrict__ hpart, int pbase,
                  int lane, int wv) {
    const int q = lane >> 4, n = lane & 15;
    const int mt0 = wv * 2;
    const bool two = (wv < 3);          // wave-uniform
    const f32x4 z4 = {0.f, 0.f, 0.f, 0.f};
    f32x4 acc0[NT], acc1[NT];
#pragma unroll
    for (int nt = 0; nt < NT; ++nt) { acc0[nt] = bs0; acc1[nt] = bs1; }
#pragma unroll
    for (int ks = 0; ks < 10; ++ks) {
        short8 a0 = *(const short8*)&Ap[(ks * 448 + mt0 * 64 + lane) * 8];
        short8 a1;
        if (two) a1 = *(const short8*)&Ap[(ks * 448 + (mt0 + 1) * 64 + lane) * 8];
        const char* bp = (const char*)s_src + bofs[ks];
#pragma unroll
        for (int nt = 0; nt < NT; ++nt) {
            short8 bf;
            if (nt < 4) bf = *(const short8*)(bp + nt * (16 * SSTR * 2));
            else        bf = *(const short8*)((const char*)s_src + bofs4[ks]);
            acc0[nt] = __builtin_amdgcn_mfma_f32_16x16x32_bf16(a0, bf, acc0[nt], 0, 0, 0);
            if (two)
                acc1[nt] = __builtin_amdgcn_mfma_f32_16x16x32_bf16(a1, bf, acc1[nt], 0, 0, 0);
        }
    }
    const int fb0 = mt0 * 16 + q * 4, fb1 = fb0 + 16;
    f32x4 ps0 = z4, ps1 = z4;
#pragma unroll
    for (int nt = 0; nt < NT; ++nt) {
        const int j = nt * 16 + n;
        f32x4 v0, v1;
#pragma unroll
        for (int r = 0; r < 4; ++r) {
            v0[r] = fmaxf(acc0[nt][r], 0.f);
            if (two) v1[r] = fmaxf(acc1[nt][r], 0.f);
        }
        if constexpr (EDGE) {
            const bool lok = (unsigned)(row0l + j) < 512u;
#pragma unroll
            for (int r = 0; r < 4; ++r) {
                v0[r] = lok ? v0[r] : 0.f;
                if (two) v1[r] = lok ? v1[r] : 0.f;
            }
        }
        if constexpr (POOL) {
            const int l = row0l + j;
            const bool pok = (l >= l0) && (l < l0 + 64);
            if (pok) {
#pragma unroll
                for (int r = 0; r < 4; ++r) {
                    ps0[r] += v0[r];
                    if (two) ps1[r] += v1[r];
                }
            }
        }
        uint2v pk0, pk1;
        pk0[0] = pk2bf(v0[0], v0[1]); pk0[1] = pk2bf(v0[2], v0[3]);
        if (two) { pk1[0] = pk2bf(v1[0], v1[1]); pk1[1] = pk2bf(v1[2], v1[3]); }
        if constexpr (TO_GLOBAL) {       // NT==4: all j < 64
            *(uint2v*)&gout[j * 112 + fb0] = pk0;
            if (two) *(uint2v*)&gout[j * 112 + fb1] = pk1;
        } else {
            if (nt < 4 || n < 6) {       // store rows j < 70 only
                *(uint2v*)&s_dst[j * SSTR + fb0] = pk0;
                if (two) *(uint2v*)&s_dst[j * SSTR + fb1] = pk1;
            }
        }
    }
    if constexpr (POOL) {
#pragma unroll
        for (int off = 1; off <= 8; off <<= 1)
#pragma unroll
            for (int r = 0; r < 4; ++r) {
                ps0[r] += __shfl_xor(ps0[r], off, 64);
                ps1[r] += __shfl_xor(ps1[r], off, 64);
            }
        if (n == 0) {
            *(f32x4*)&hpart[pbase * 112 + fb0] = ps0;
            if (two) *(f32x4*)&hpart[pbase * 112 + fb1] = ps1;
        }
    }
}

// ---------------------------------------------------------------------------
// Fused conv1 -> conv2 -> li, 64-wide l-tile, 256 threads (4 waves).
// LDS 2*72*SSTR*2 = 39168 B -> 4 blocks/CU. B-offset table computed once.
// Interior blocks (bx 1..6) skip all range clamping (EDGE=false).
// ---------------------------------------------------------------------------
__global__ __launch_bounds__(256, 4) void fused_conv_kernel(
    const int* __restrict__ xidx, const short* __restrict__ embT,
    const short* __restrict__ A1, const short* __restrict__ A2,
    const short* __restrict__ A3,
    const float* __restrict__ b1, const float* __restrict__ b2,
    const float* __restrict__ b3,
    short* __restrict__ locT, float* __restrict__ hpart) {
    extern __shared__ char smem[];
    short* s_e = (short*)smem;                    // [72][SSTR], later c2
    short* s_h = (short*)(smem + 72 * SSTR * 2);  // [72][SSTR]
    const int tid = threadIdx.x;
    const int b = blockIdx.y, bx = blockIdx.x, l0 = bx * 64;
    const int lane = tid & 63, wv = tid >> 6;
    const int q = lane >> 4, n = lane & 15;

    // stage e: 70 rows x 14 b128 chunks (virtual 16-grid; c8>=14 skipped)
#pragma unroll
    for (int p = 0; p < 5; ++p) {
        int idx = tid + p * 256;           // 0..1279, need j<70
        int j = idx >> 4, c8 = idx & 15;
        if (j < 70 && c8 < 14) {
            int lg = l0 - 3 + j;
            short8 v = {0, 0, 0, 0, 0, 0, 0, 0};
            if (lg >= 0 && lg < 512) {
                int row = xidx[b * 512 + lg];
                v = *(const short8*)&embT[row * 112 + c8 * 8];
            }
            *(short8*)&s_e[j * SSTR + c8 * 8] = v;
        }
    }

    // per-lane B offsets (bytes) for all 10 k-steps, used by all 3 passes
    int bofs[10], bofs4[10];
#pragma unroll
    for (int ks = 0; ks < 10; ++ks) {
        int oct = ks * 4 + q;
        int dk = (oct >= 39) ? 3 : (oct >= 26) ? 2 : (oct >= 13) ? 1 : 0;
        int c0 = (oct - 13 * dk) * 8;
        bofs[ks] = ((n + dk) * SSTR + c0) * 2;
        int r4 = 64 + n + dk; if (r4 > 69) r4 = 69;  // discarded rows only
        bofs4[ks] = (r4 * SSTR + c0) * 2;
    }
    const int fb0 = wv * 32 + q * 4, fb1 = fb0 + 16;
    const f32x4 z4 = {0.f, 0.f, 0.f, 0.f};
    f32x4 bsA0 = (fb0 < 100) ? *(const f32x4*)&b1[fb0] : z4;
    f32x4 bsA1 = (fb1 < 100) ? *(const f32x4*)&b1[fb1] : z4;
    f32x4 bsB0 = (fb0 < 100) ? *(const f32x4*)&b2[fb0] : z4;
    f32x4 bsB1 = (fb1 < 100) ? *(const f32x4*)&b2[fb1] : z4;
    f32x4 bsC0 = (fb0 < 100) ? *(const f32x4*)&b3[fb0] : z4;
    f32x4 bsC1 = (fb1 < 100) ? *(const f32x4*)&b3[fb1] : z4;

    __syncthreads();
    const bool edge = (bx == 0) || (bx == 7);
    if (edge) {
        conv3tap<5, true, false, true>(A1, s_e, s_h, nullptr, bofs, bofs4,
                                       bsA0, bsA1, l0 - 2, l0, hpart,
                                       b * 8 + bx, lane, wv);
        __syncthreads();
        conv3tap<5, false, false, true>(A2, s_h, s_e, nullptr, bofs, bofs4,
                                        bsB0, bsB1, l0 - 1, l0, nullptr, 0,
                                        lane, wv);
    } else {
        conv3tap<5, true, false, false>(A1, s_e, s_h, nullptr, bofs, bofs4,
                                        bsA0, bsA1, l0 - 2, l0, hpart,
                                        b * 8 + bx, lane, wv);
        __syncthreads();
        conv3tap<5, false, false, false>(A2, s_h, s_e, nullptr, bofs, bofs4,
                                         bsB0, bsB1, l0 - 1, l0, nullptr, 0,
                                         lane, wv);
    }
    __syncthreads();
    // li: outputs l in [l0, l0+63] always valid -> EDGE=false
    conv3tap<4, false, true, false>(A3, s_e, nullptr,
                                    locT + ((size_t)b * 512 + l0) * 112,
                                    bofs, bofs4, bsC0, bsC1, l0, l0,
                                    nullptr, 0, lane, wv);
}

// ---------------------------------------------------------------------------
// conv3 (1x1, loc half) + conv4 fused -> logits. 128-l tile; mt-split;
// accumulator initialized with zg (bias+gate folded). DS imm offsets.
// LDS 128*SSTR*2 + 4*128*4 = 36864 B -> 4 blocks/CU.
// ---------------------------------------------------------------------------
__global__ __launch_bounds__(256, 4) void conv3_logits_kernel(
    const short* __restrict__ locT, const short* __restrict__ A4,
    const float* __restrict__ zg, const float* __restrict__ w4,
    const float* __restrict__ b4, float* __restrict__ logits) {
    extern __shared__ char smem[];
    short* s_in = (short*)smem;                       // [128][SSTR]
    float* s_part = (float*)(smem + 128 * SSTR * 2);  // [4][128]
    const int tid = threadIdx.x;
    const int b = blockIdx.y, l0r = blockIdx.x * 128;
    const int lane = tid & 63, wv = tid >> 6;
    const int q = lane >> 4, n = lane & 15;

    // stage 128 rows x 14 b128 chunks (virtual 16-grid), register-batched
    {
        short8 tmp[8];
#pragma unroll
        for (int p = 0; p < 8; ++p) {
            int idx = tid + p * 256;
            int j = idx >> 4, c8 = idx & 15;
            if (c8 < 14)
                tmp[p] = *(const short8*)&locT[((size_t)b * 512 + l0r + j) * 112 + c8 * 8];
        }
#pragma unroll
        for (int p = 0; p < 8; ++p) {
            int idx = tid + p * 256;
            int j = idx >> 4, c8 = idx & 15;
            if (c8 < 14)
                *(short8*)&s_in[j * SSTR + c8 * 8] = tmp[p];
        }
    }
    const f32x4 z4 = {0.f, 0.f, 0.f, 0.f};
    const int mt0 = wv * 2;
    const bool two = (wv < 3);
    const int fb0 = mt0 * 16 + q * 4, fb1 = fb0 + 16;
    f32x4 zg0 = *(const f32x4*)&zg[b * 112 + fb0];
    f32x4 zg1 = two ? *(const f32x4*)&zg[b * 112 + fb1] : z4;
    f32x4 acc0[8], acc1[8];
#pragma unroll
    for (int nt = 0; nt < 8; ++nt) { acc0[nt] = zg0; acc1[nt] = zg1; }
    __syncthreads();

#pragma unroll
    for (int ks = 0; ks < 4; ++ks) {
        short8 a0 = *(const short8*)&A4[(ks * 448 + mt0 * 64 + lane) * 8];
        short8 a1;
        if (two) a1 = *(const short8*)&A4[(ks * 448 + (mt0 + 1) * 64 + lane) * 8];
        int c0 = (ks * 4 + q) * 8;
        if (c0 > 104) c0 = 104;   // A zero for kappa>=100; col 104..111 zero
        const short* bptr = s_in + n * SSTR + c0;
#pragma unroll
        for (int nt = 0; nt < 8; ++nt) {
            short8 bf = *(const short8*)(bptr + nt * 16 * SSTR);  // DS imm
            acc0[nt] = __builtin_amdgcn_mfma_f32_16x16x32_bf16(a0, bf, acc0[nt], 0, 0, 0);
            if (two)
                acc1[nt] = __builtin_amdgcn_mfma_f32_16x16x32_bf16(a1, bf, acc1[nt], 0, 0, 0);
        }
    }
    f32x4 w40 = (fb0 < 100) ? *(const f32x4*)&w4[fb0] : z4;
    f32x4 w41 = (two && fb1 < 100) ? *(const f32x4*)&w4[fb1] : z4;
#pragma unroll
    for (int nt = 0; nt < 8; ++nt) {
        float part = 0.f;
#pragma unroll
        for (int r = 0; r < 4; ++r) {
            part += fmaxf(acc0[nt][r], 0.f) * w40[r];
            if (two) part += fmaxf(acc1[nt][r], 0.f) * w41[r];
        }
        part += __shfl_xor(part, 16, 64);
        part += __shfl_xor(part, 32, 64);
        if (q == 0) s_part[wv * 128 + nt * 16 + n] = part;
    }
    __syncthreads();
    if (tid < 128) {
        float s = s_part[tid] + s_part[128 + tid] + s_part[256 + tid] +
                  s_part[384 + tid] + b4[0];
        logits[b * 512 + l0r + tid] = s;
    }
}

// ---------------------------------------------------------------------------
// Finish pool: hm = sum over 8 sub-block partials / 512, gate MLP, fold g:
// zg[b,f] = conv3_b[f] + sum_h g[b,h] * w3[f][h]   (f>=100 -> 0)
// ---------------------------------------------------------------------------
__global__ __launch_bounds__(128) void pool_gate_kernel(
    const float* __restrict__ hpart, const float* __restrict__ gi_w,
    const float* __restrict__ gi_b, const float* __restrict__ w3,
    const float* __restrict__ b3, float* __restrict__ zg) {
    int b = blockIdx.x, tid = threadIdx.x;
    __shared__ float s_hm[112];
    __shared__ float s_g[100];
    if (tid < 112) {
        float a = 0.f;
#pragma unroll
        for (int s = 0; s < 8; ++s) a += hpart[(b * 8 + s) * 112 + tid];
        s_hm[tid] = a * (1.f / 512.f);
    }
    __syncthreads();
    if (tid < 100) {
        float a = gi_b[tid];
        for (int f = 0; f < 100; ++f) a += s_hm[f] * gi_w[tid * 100 + f];
        s_g[tid] = fmaxf(a, 0.f);
    }
    __syncthreads();
    if (tid < 112) {
        float a = 0.f;
        if (tid < 100) {
            a = b3[tid];
            for (int h = 0; h < 100; ++h) a += s_g[h] * w3[tid * 200 + h];
        }
        zg[b * 112 + tid] = a;
    }
}

// ---------------------------------------------------------------------------
// Fused sampler + distil head, one block per b.
// csamples[b,l] = max_k softmax_l((gumbel+logit)/T) -> cs_out AND kept in
// LDS; pooled = mean_l embT[x[l]]*cs[l] (bf16 gather); fc1 relu; sigmoid.
// ---------------------------------------------------------------------------
__global__ __launch_bounds__(256) void samp_head_kernel(
    const float* __restrict__ u, const float* __restrict__ logits,
    const int* __restrict__ xidx, const short* __restrict__ embT,
    const float* __restrict__ f1w, const float* __restrict__ f1b,
    const float* __restrict__ hw, const float* __restrict__ hb,
    float* __restrict__ cs_out, float* __restrict__ out) {
    const float EPSV = 1.1920929e-07f;
    int b = blockIdx.x, tid = threadIdx.x;
    int lane = tid & 63, wv = tid >> 6;
    __shared__ float s_log[512], s_cs[512], s_red[8];
    __shared__ int s_x[512];
    __shared__ float s_acc[16][112];
    __shared__ float s_pool[112], s_h2[100], s_fin[4];
    float uu[20];
#pragma unroll
    for (int k = 0; k < 10; ++k) {
        uu[k * 2]     = u[(b * 10 + k) * 512 + tid];
        uu[k * 2 + 1] = u[(b * 10 + k) * 512 + tid + 256];
    }
    for (int l = tid; l < 512; l += 256) {
        s_log[l] = logits[b * 512 + l];
        s_cs[l] = 0.f;
        s_x[l] = xidx[b * 512 + l];
    }
    __syncthreads();
    for (int k = 0; k < 10; ++k) {
        float nz[2];
#pragma unroll
        for (int i = 0; i < 2; ++i) {
            int l = tid + i * 256;
            float vv = fminf(fmaxf(uu[k * 2 + i], EPSV), 1.f - EPSV);
            float g = -__logf(-__logf(vv));
            nz[i] = (g + s_log[l]) * (1.f / 0.3f);
        }
        float m = fmaxf(nz[0], nz[1]);
#pragma unroll
        for (int off = 32; off >= 1; off >>= 1) m = fmaxf(m, __shfl_xor(m, off, 64));
        if (lane == 0) s_red[wv] = m;
        __syncthreads();
        m = fmaxf(fmaxf(s_red[0], s_red[1]), fmaxf(s_red[2], s_red[3]));
        float e0 = __expf(nz[0] - m), e1 = __expf(nz[1] - m);
        float s = e0 + e1;
#pragma unroll
        for (int off = 32; off >= 1; off >>= 1) s += __shfl_xor(s, off, 64);
        if (lane == 0) s_red[4 + wv] = s;
        __syncthreads();
        float inv = 1.f / (s_red[4] + s_red[5] + s_red[6] + s_red[7]);
        s_cs[tid]       = fmaxf(s_cs[tid],       e0 * inv);
        s_cs[tid + 256] = fmaxf(s_cs[tid + 256], e1 * inv);
    }
    for (int l = tid; l < 512; l += 256) cs_out[b * 512 + l] = s_cs[l];
    __syncthreads();
    // pooled partial sums: thread (jg, c8) covers l = jg+16t, channels c8*8..+7
    int jg = tid >> 4, c8 = tid & 15;
    if (c8 < 14) {
        f32x4 pa = {0.f, 0.f, 0.f, 0.f}, pb = {0.f, 0.f, 0.f, 0.f};
#pragma unroll 4
        for (int l = jg; l < 512; l += 16) {
            int row = s_x[l];
            float cv = s_cs[l];
            short8 e8 = *(const short8*)&embT[(size_t)row * 112 + c8 * 8];
#pragma unroll
            for (int r = 0; r < 4; ++r) {
                pa[r] += cv * bfu(e8[r]);
                pb[r] += cv * bfu(e8[4 + r]);
            }
        }
        *(f32x4*)&s_acc[jg][c8 * 8] = pa;
        *(f32x4*)&s_acc[jg][c8 * 8 + 4] = pb;
    }
    __syncthreads();
    if (tid < 112) {
        float p = 0.f;
#pragma unroll
        for (int g = 0; g < 16; ++g) p += s_acc[g][tid];
        s_pool[tid] = p * (1.f / 512.f);
    }
    __syncthreads();
    if (tid < 100) {
        float a = f1b[tid];
        for (int i = 0; i < 100; ++i) a += s_pool[i] * f1w[tid * 100 + i];
        s_h2[tid] = fmaxf(a, 0.f);
    }
    __syncthreads();
    float v = (tid < 100) ? s_h2[tid] * hw[tid] : 0.f;
#pragma unroll
    for (int off = 32; off >= 1; off >>= 1) v += __shfl_xor(v, off, 64);
    if (lane == 0) s_fin[wv] = v;
    __syncthreads();
    if (tid == 0) {
        float z = s_fin[0] + s_fin[1] + s_fin[2] + s_fin[3] + hb[0];
        out[b] = 1.f / (1.f + __expf(-z));
    }
}

// ---------------------------------------------------------------------------
extern "C" void kernel_launch(void* const* d_in, const int* in_sizes, int n_in,
                              void* d_out, int out_size, void* d_ws, size_t ws_size,
                              hipStream_t stream) {
    const int*   x   = (const int*)d_in[0];
    const float* u   = (const float*)d_in[1];
    const float* emb = (const float*)d_in[2];
    const float* c1w = (const float*)d_in[3];
    const float* c1b = (const float*)d_in[4];
    const float* giw = (const float*)d_in[5];
    const float* gib = (const float*)d_in[6];
    const float* c2w = (const float*)d_in[7];
    const float* c2b = (const float*)d_in[8];
    const float* liw = (const float*)d_in[9];
    const float* lib = (const float*)d_in[10];
    const float* c3w = (const float*)d_in[11];
    const float* c3b = (const float*)d_in[12];
    const float* c4w = (const float*)d_in[13];
    const float* c4b = (const float*)d_in[14];
    const float* f1w = (const float*)d_in[15];
    const float* f1b = (const float*)d_in[16];
    const float* hww = (const float*)d_in[17];
    const float* hbb = (const float*)d_in[18];
    float* out = (float*)d_out;

    char* ws = (char*)d_ws;
    short* locT   = (short*)(ws + 0);           // [512][512][112] bf16 (58.7 MB)
    short* embT   = (short*)(ws + 58720256);    // [100000][112] bf16 (22.4 MB)
    short* A1     = (short*)(ws + 81120256);    // 10*448*16 B each
    short* A2     = (short*)(ws + 81191936);
    short* A3     = (short*)(ws + 81263616);
    short* A4     = (short*)(ws + 81335296);    // 4*448*16 B
    float* zg     = (float*)(ws + 81363968);    // [512][112]
    float* logits = (float*)(ws + 81593344);    // [512][512]
    float* hpart  = (float*)(ws + 82641920);    // [512][8][112]

    emb_cvt_kernel<<<12500, 256, 0, stream>>>(emb, embT);
    pack_all_kernel<<<238, 64, 0, stream>>>(c1w, c2w, liw, c3w, A1, A2, A3, A4);

    size_t smemA = 2 * 72 * SSTR * 2;             // 39168 B -> 4 blocks/CU
    fused_conv_kernel<<<dim3(8, 512), 256, smemA, stream>>>(
        x, embT, A1, A2, A3, c1b, c2b, lib, locT, hpart);
    pool_gate_kernel<<<512, 128, 0, stream>>>(hpart, giw, gib, c3w, c3b, zg);
    size_t smemB = 128 * SSTR * 2 + 4 * 128 * 4;  // 36864 B -> 4 blocks/CU
    conv3_logits_kernel<<<dim3(4, 512), 256, smemB, stream>>>(
        locT, A4, zg, c4w, c4b, logits);
    samp_head_kernel<<<512, 256, 0, stream>>>(
        u, logits, x, embT, f1w, f1b, hww, hbb, out + 512, out);
}

// Round 8
// 253.777 us; speedup vs baseline: 2.1237x; 1.0922x over previous
//
#include <hip/hip_runtime.h>
#include <math.h>

#define DEV __device__ __forceinline__

typedef __attribute__((ext_vector_type(8))) short short8;
typedef __attribute__((ext_vector_type(4))) short short4v;
typedef __attribute__((ext_vector_type(4))) float f32x4;
typedef __attribute__((ext_vector_type(2))) unsigned uint2v;

// LDS row stride in shorts (272 B = 68 words; 68 mod 32 = 4 -> b128 reads
// land 2-way on banks = free per m136).
#define SSTR 136
#define ROWB (16 * SSTR * 2)   // 4352 B per 16-row tile

DEV short f2bf(float f) {
    unsigned u = __builtin_bit_cast(unsigned, f);
    unsigned r = (u + 0x7fffu + ((u >> 16) & 1u)) >> 16;
    return (short)r;
}

#if __has_builtin(__builtin_amdgcn_cvt_pk_bf16_f32)
DEV unsigned pk2bf(float a, float b) {
    auto v = __builtin_amdgcn_cvt_pk_bf16_f32(a, b);
    return __builtin_bit_cast(unsigned, v);
}
#else
DEV unsigned pk2bf(float a, float b) {
    return ((unsigned)(unsigned short)f2bf(a)) |
           (((unsigned)(unsigned short)f2bf(b)) << 16);
}
#endif

DEV float bfu(short s) {
    unsigned u = ((unsigned)(unsigned short)s) << 16;
    return __builtin_bit_cast(float, u);
}

// ---------------------------------------------------------------------------
// emb f32 [V][100] -> bf16 [V][112], cols 100..111 zeroed. 8 rows/block.
// ---------------------------------------------------------------------------
__global__ __launch_bounds__(256) void emb_cvt_kernel(
    const float* __restrict__ emb, short* __restrict__ embT) {
    int t = threadIdx.x;
    int row = blockIdx.x * 8 + (t >> 5);
    int c4 = t & 31;
    if (c4 >= 28) return;
    short4v v = {0, 0, 0, 0};
    if (c4 < 25) {
        f32x4 e = *(const f32x4*)&emb[row * 100 + c4 * 4];
#pragma unroll
        for (int r = 0; r < 4; ++r) v[r] = f2bf(e[r]);
    }
    *(short4v*)&embT[row * 112 + c4 * 4] = v;
}

// ---------------------------------------------------------------------------
// Pack conv weights into MFMA A-fragment order.
// mode 0 (3-tap): 13 octets per tap -> kappa: oct=kk>>3, dk=oct/13,
//   c=(oct-13*dk)*8+(kk&7); K = 320 (10 ks), oct 39 zero.
// mode 1 (conv3 loc half): kappa = c (cols 100..199 of w[100][200]), K 128.
// ---------------------------------------------------------------------------
__global__ __launch_bounds__(64) void pack_all_kernel(
    const float* __restrict__ c1w, const float* __restrict__ c2w,
    const float* __restrict__ liw, const float* __restrict__ c3w,
    short* __restrict__ A1, short* __restrict__ A2,
    short* __restrict__ A3, short* __restrict__ A4) {
    int bx = blockIdx.x;
    const float* w; short* dst; int mode, lbx;
    if (bx < 70)       { w = c1w; dst = A1; mode = 0; lbx = bx; }
    else if (bx < 140) { w = c2w; dst = A2; mode = 0; lbx = bx - 70; }
    else if (bx < 210) { w = liw; dst = A3; mode = 0; lbx = bx - 140; }
    else               { w = c3w; dst = A4; mode = 1; lbx = bx - 210; }
    int lane = threadIdx.x;
    int f = lbx % 7 * 16 + (lane & 15);
    int kb = (lbx / 7) * 32 + (lane >> 4) * 8;
    short8 v;
#pragma unroll
    for (int j = 0; j < 8; ++j) {
        int kk = kb + j;
        float val = 0.f;
        if (f < 100) {
            if (mode == 0) {
                int oct = kk >> 3, dk = oct / 13;
                int c = (oct - 13 * dk) * 8 + (kk & 7);
                if (dk < 3 && c < 100) val = w[(f * 100 + c) * 3 + dk];
            } else {
                if (kk < 100) val = w[f * 200 + 100 + kk];
            }
        }
        v[j] = f2bf(val);
    }
    *(short8*)&dst[(lbx * 64 + lane) * 8] = v;
}

// ---------------------------------------------------------------------------
// One 3-tap conv pass, BALANCED tile: this wave owns mt [MTB,MTB+MT) x
// nt [NTB,NTB+NT). B-reads amortize over MT MFMAs (was 2), A-rows over NT.
// Accumulator init = bias (free add). CLAMPL: the nt==4 tile reads clamped
// rows (feeds only discarded outputs; halo chain loc<=63 -> c2<=65 ->
// h<=67 -> e<=69 all real). EDGE: l-range zeroing only in bx 0/7.
// POOL: relu partial sums for l in [l0,l0+64) -> hpart_slot[112].
// ---------------------------------------------------------------------------
template<int MT, int NT, int MTB, int NTB, bool CLAMPL, bool POOL,
         bool TO_GLOBAL, bool EDGE>
DEV void ctap(const short* __restrict__ Ap, const short* s_src, short* s_dst,
              short* __restrict__ gout, const int* bofs, const int* bofs4,
              const float* __restrict__ bias, int row0l, int l0,
              float* __restrict__ hpart_slot, int lane) {
    const int q = lane >> 4, n = lane & 15;
    const f32x4 z4 = {0.f, 0.f, 0.f, 0.f};
    f32x4 acc[MT][NT];
#pragma unroll
    for (int mt = 0; mt < MT; ++mt) {
        int fb = (MTB + mt) * 16 + q * 4;
        f32x4 bs = (fb < 100) ? *(const f32x4*)&bias[fb] : z4;
#pragma unroll
        for (int nt = 0; nt < NT; ++nt) acc[mt][nt] = bs;
    }
#pragma unroll
    for (int ks = 0; ks < 10; ++ks) {
        short8 a[MT];
#pragma unroll
        for (int mt = 0; mt < MT; ++mt)
            a[mt] = *(const short8*)&Ap[(ks * 448 + (MTB + mt) * 64 + lane) * 8];
        const char* bp = (const char*)s_src + bofs[ks];
        short8 bf[NT];
#pragma unroll
        for (int nt = 0; nt < NT; ++nt) {
            if (CLAMPL && (NTB + nt) == 4)
                bf[nt] = *(const short8*)((const char*)s_src + bofs4[ks]);
            else
                bf[nt] = *(const short8*)(bp + (NTB + nt) * ROWB);
        }
#pragma unroll
        for (int mt = 0; mt < MT; ++mt)
#pragma unroll
            for (int nt = 0; nt < NT; ++nt)
                acc[mt][nt] = __builtin_amdgcn_mfma_f32_16x16x32_bf16(
                    a[mt], bf[nt], acc[mt][nt], 0, 0, 0);
    }
    f32x4 ps[MT];
    if constexpr (POOL) {
#pragma unroll
        for (int mt = 0; mt < MT; ++mt) ps[mt] = z4;
    }
#pragma unroll
    for (int nt = 0; nt < NT; ++nt) {
        const int j = (NTB + nt) * 16 + n;
        const int l = row0l + j;
        bool lok = true;
        if constexpr (EDGE) lok = ((unsigned)l < 512u);
        const bool pok = POOL && (l >= l0) && (l < l0 + 64);
#pragma unroll
        for (int mt = 0; mt < MT; ++mt) {
            const int fb = (MTB + mt) * 16 + q * 4;
            f32x4 v;
#pragma unroll
            for (int r = 0; r < 4; ++r) {
                v[r] = fmaxf(acc[mt][nt][r], 0.f);
                if constexpr (EDGE) v[r] = lok ? v[r] : 0.f;
            }
            if constexpr (POOL) {
                if (pok) {
#pragma unroll
                    for (int r = 0; r < 4; ++r) ps[mt][r] += v[r];
                }
            }
            uint2v pk;
            pk[0] = pk2bf(v[0], v[1]); pk[1] = pk2bf(v[2], v[3]);
            if constexpr (TO_GLOBAL) {
                *(uint2v*)&gout[j * 112 + fb] = pk;
            } else {
                if ((NTB + nt) < 4 || n < 6)      // store rows j < 70 only
                    *(uint2v*)&s_dst[j * SSTR + fb] = pk;
            }
        }
    }
    if constexpr (POOL) {
#pragma unroll
        for (int mt = 0; mt < MT; ++mt)
#pragma unroll
            for (int off = 1; off <= 8; off <<= 1)
#pragma unroll
                for (int r = 0; r < 4; ++r)
                    ps[mt][r] += __shfl_xor(ps[mt][r], off, 64);
        if (n == 0) {
#pragma unroll
            for (int mt = 0; mt < MT; ++mt)
                *(f32x4*)&hpart_slot[(MTB + mt) * 16 + q * 4] = ps[mt];
        }
    }
}

// ---------------------------------------------------------------------------
// Fused conv1 -> conv2 -> li, 64-wide l-tile, 256 threads (4 waves).
// Balanced (mt,nt) wave tiles: wv0=(4,3)@(0,0) wv1=(4,2)@(0,3)
// wv2=(3,3)@(4,0) wv3=(3,2)@(4,3); li: NT=2 each @(0/4, 0/2).
// LDS 2*72*SSTR*2 = 39168 B -> 4 blocks/CU.
// ---------------------------------------------------------------------------
__global__ __launch_bounds__(256, 4) void fused_conv_kernel(
    const int* __restrict__ xidx, const short* __restrict__ embT,
    const short* __restrict__ A1, const short* __restrict__ A2,
    const short* __restrict__ A3,
    const float* __restrict__ b1, const float* __restrict__ b2,
    const float* __restrict__ b3,
    short* __restrict__ locT, float* __restrict__ hpart) {
    extern __shared__ char smem[];
    short* s_e = (short*)smem;                    // [72][SSTR], later c2
    short* s_h = (short*)(smem + 72 * SSTR * 2);  // [72][SSTR]
    const int tid = threadIdx.x;
    const int b = blockIdx.y, bx = blockIdx.x, l0 = bx * 64;
    const int lane = tid & 63, wv = tid >> 6;
    const int q = lane >> 4, n = lane & 15;

    // stage e: 70 rows x 14 b128 chunks (virtual 16-grid; c8>=14 skipped)
#pragma unroll
    for (int p = 0; p < 5; ++p) {
        int idx = tid + p * 256;           // 0..1279, need j<70
        int j = idx >> 4, c8 = idx & 15;
        if (j < 70 && c8 < 14) {
            int lg = l0 - 3 + j;
            short8 v = {0, 0, 0, 0, 0, 0, 0, 0};
            if (lg >= 0 && lg < 512) {
                int row = xidx[b * 512 + lg];
                v = *(const short8*)&embT[row * 112 + c8 * 8];
            }
            *(short8*)&s_e[j * SSTR + c8 * 8] = v;
        }
    }

    // per-lane B byte offsets for all 10 k-steps (row n+dk, col c0)
    int bofs[10], bofs4[10];
#pragma unroll
    for (int ks = 0; ks < 10; ++ks) {
        int oct = ks * 4 + q;
        int dk = (oct >= 39) ? 3 : (oct >= 26) ? 2 : (oct >= 13) ? 1 : 0;
        int c0 = (oct - 13 * dk) * 8;
        bofs[ks] = ((n + dk) * SSTR + c0) * 2;
        int r4 = 64 + n + dk; if (r4 > 69) r4 = 69;  // discarded rows only
        bofs4[ks] = (r4 * SSTR + c0) * 2;
    }
    float* hps = hpart + ((b * 8 + bx) * 2 + (wv & 1)) * 112;
    short* gouts = locT + ((size_t)b * 512 + l0) * 112;

    __syncthreads();
    const bool edge = (bx == 0) || (bx == 7);

#define PASS3T(Ap, SRC, DST, BIAS, R0L, PL, E)                                   \
    if (wv == 0)      ctap<4,3,0,0,false,PL,false,E>(Ap,SRC,DST,nullptr,bofs,bofs4,BIAS,R0L,l0,hps,lane); \
    else if (wv == 1) ctap<4,2,0,3,true, PL,false,E>(Ap,SRC,DST,nullptr,bofs,bofs4,BIAS,R0L,l0,hps,lane); \
    else if (wv == 2) ctap<3,3,4,0,false,PL,false,E>(Ap,SRC,DST,nullptr,bofs,bofs4,BIAS,R0L,l0,hps,lane); \
    else              ctap<3,2,4,3,true, PL,false,E>(Ap,SRC,DST,nullptr,bofs,bofs4,BIAS,R0L,l0,hps,lane);

    if (edge) {
        PASS3T(A1, s_e, s_h, b1, l0 - 2, true, true)
        __syncthreads();
        PASS3T(A2, s_h, s_e, b2, l0 - 1, false, true)
    } else {
        PASS3T(A1, s_e, s_h, b1, l0 - 2, true, false)
        __syncthreads();
        PASS3T(A2, s_h, s_e, b2, l0 - 1, false, false)
    }
    __syncthreads();
    // li: outputs l in [l0, l0+63] always valid
    if (wv == 0)      ctap<4,2,0,0,false,false,true,false>(A3,s_e,nullptr,gouts,bofs,bofs4,b3,l0,l0,hps,lane);
    else if (wv == 1) ctap<4,2,0,2,false,false,true,false>(A3,s_e,nullptr,gouts,bofs,bofs4,b3,l0,l0,hps,lane);
    else if (wv == 2) ctap<3,2,4,0,false,false,true,false>(A3,s_e,nullptr,gouts,bofs,bofs4,b3,l0,l0,hps,lane);
    else              ctap<3,2,4,2,false,false,true,false>(A3,s_e,nullptr,gouts,bofs,bofs4,b3,l0,l0,hps,lane);
#undef PASS3T
}

// ---------------------------------------------------------------------------
// conv3 (1x1, loc half) + conv4 fused -> logits. 128-l tile; balanced:
// wv0=(4mt@0, nt0-3) wv1=(4mt@0, nt4-7) wv2=(3mt@4, nt0-3) wv3=(3mt@4,nt4-7).
// acc init = zg. Cross-f partials in s_part[2][128].
// LDS 128*SSTR*2 + 1024 = 35840 B -> 4 blocks/CU.
// ---------------------------------------------------------------------------
template<int MT, int MTB, int NTB, int SLOT>
DEV void c3tile(const short* s_in, float* s_part, const short* __restrict__ A4,
                const float* __restrict__ zg, const float* __restrict__ w4,
                int bb, int lane) {
    const int q = lane >> 4, n = lane & 15;
    const f32x4 z4 = {0.f, 0.f, 0.f, 0.f};
    f32x4 acc[MT][4];
#pragma unroll
    for (int mt = 0; mt < MT; ++mt) {
        int fb = (MTB + mt) * 16 + q * 4;
        f32x4 zgv = *(const f32x4*)&zg[bb * 112 + fb];  // pad entries are 0
#pragma unroll
        for (int nt = 0; nt < 4; ++nt) acc[mt][nt] = zgv;
    }
#pragma unroll
    for (int ks = 0; ks < 4; ++ks) {
        short8 a[MT];
#pragma unroll
        for (int mt = 0; mt < MT; ++mt)
            a[mt] = *(const short8*)&A4[(ks * 448 + (MTB + mt) * 64 + lane) * 8];
        int c0 = (ks * 4 + q) * 8;
        if (c0 > 104) c0 = 104;   // A zero for kappa>=100
        const char* bp = (const char*)(s_in + n * SSTR + c0);
        short8 bf[4];
#pragma unroll
        for (int nt = 0; nt < 4; ++nt)
            bf[nt] = *(const short8*)(bp + (NTB + nt) * ROWB);
#pragma unroll
        for (int mt = 0; mt < MT; ++mt)
#pragma unroll
            for (int nt = 0; nt < 4; ++nt)
                acc[mt][nt] = __builtin_amdgcn_mfma_f32_16x16x32_bf16(
                    a[mt], bf[nt], acc[mt][nt], 0, 0, 0);
    }
#pragma unroll
    for (int nt = 0; nt < 4; ++nt) {
        float part = 0.f;
#pragma unroll
        for (int mt = 0; mt < MT; ++mt) {
            const int fb = (MTB + mt) * 16 + q * 4;
            f32x4 w4v = (fb < 100) ? *(const f32x4*)&w4[fb] : z4;
#pragma unroll
            for (int r = 0; r < 4; ++r)
                part += fmaxf(acc[mt][nt][r], 0.f) * w4v[r];
        }
        part += __shfl_xor(part, 16, 64);
        part += __shfl_xor(part, 32, 64);
        if (q == 0) s_part[SLOT * 128 + (NTB + nt) * 16 + n] = part;
    }
}

__global__ __launch_bounds__(256, 4) void conv3_logits_kernel(
    const short* __restrict__ locT, const short* __restrict__ A4,
    const float* __restrict__ zg, const float* __restrict__ w4,
    const float* __restrict__ b4, float* __restrict__ logits) {
    extern __shared__ char smem[];
    short* s_in = (short*)smem;                       // [128][SSTR]
    float* s_part = (float*)(smem + 128 * SSTR * 2);  // [2][128]
    const int tid = threadIdx.x;
    const int b = blockIdx.y, l0r = blockIdx.x * 128;
    const int lane = tid & 63, wv = tid >> 6;

    {
        short8 tmp[8];
#pragma unroll
        for (int p = 0; p < 8; ++p) {
            int idx = tid + p * 256;
            int j = idx >> 4, c8 = idx & 15;
            if (c8 < 14)
                tmp[p] = *(const short8*)&locT[((size_t)b * 512 + l0r + j) * 112 + c8 * 8];
        }
#pragma unroll
        for (int p = 0; p < 8; ++p) {
            int idx = tid + p * 256;
            int j = idx >> 4, c8 = idx & 15;
            if (c8 < 14)
                *(short8*)&s_in[j * SSTR + c8 * 8] = tmp[p];
        }
    }
    __syncthreads();
    if (wv == 0)      c3tile<4, 0, 0, 0>(s_in, s_part, A4, zg, w4, b, lane);
    else if (wv == 1) c3tile<4, 0, 4, 0>(s_in, s_part, A4, zg, w4, b, lane);
    else if (wv == 2) c3tile<3, 4, 0, 1>(s_in, s_part, A4, zg, w4, b, lane);
    else              c3tile<3, 4, 4, 1>(s_in, s_part, A4, zg, w4, b, lane);
    __syncthreads();
    if (tid < 128)
        logits[b * 512 + l0r + tid] = s_part[tid] + s_part[128 + tid] + b4[0];
}

// ---------------------------------------------------------------------------
// Finish pool: hm = sum over 16 wave-slot partials / 512, gate MLP, fold g:
// zg[b,f] = conv3_b[f] + sum_h g[b,h] * w3[f][h]   (f>=100 -> 0)
// ---------------------------------------------------------------------------
__global__ __launch_bounds__(128) void pool_gate_kernel(
    const float* __restrict__ hpart, const float* __restrict__ gi_w,
    const float* __restrict__ gi_b, const float* __restrict__ w3,
    const float* __restrict__ b3, float* __restrict__ zg) {
    int b = blockIdx.x, tid = threadIdx.x;
    __shared__ float s_hm[112];
    __shared__ float s_g[100];
    if (tid < 112) {
        float a = 0.f;
#pragma unroll
        for (int s = 0; s < 16; ++s) a += hpart[(b * 16 + s) * 112 + tid];
        s_hm[tid] = a * (1.f / 512.f);
    }
    __syncthreads();
    if (tid < 100) {
        float a = gi_b[tid];
        for (int f = 0; f < 100; ++f) a += s_hm[f] * gi_w[tid * 100 + f];
        s_g[tid] = fmaxf(a, 0.f);
    }
    __syncthreads();
    if (tid < 112) {
        float a = 0.f;
        if (tid < 100) {
            a = b3[tid];
            for (int h = 0; h < 100; ++h) a += s_g[h] * w3[tid * 200 + h];
        }
        zg[b * 112 + tid] = a;
    }
}

// ---------------------------------------------------------------------------
// Fused sampler + distil head, one block per b. Wave-parallel over k:
// wave wv handles k = wv, wv+4, wv+8 (<10) with wave-local shuffle softmax
// (no barriers inside the k loop). Merge via LDS max, then pooled gather
// (bf16 embT), fc1 relu, sigmoid head.
// ---------------------------------------------------------------------------
__global__ __launch_bounds__(256) void samp_head_kernel(
    const float* __restrict__ u, const float* __restrict__ logits,
    const int* __restrict__ xidx, const short* __restrict__ embT,
    const float* __restrict__ f1w, const float* __restrict__ f1b,
    const float* __restrict__ hw, const float* __restrict__ hb,
    float* __restrict__ cs_out, float* __restrict__ out) {
    const float EPSV = 1.1920929e-07f;
    const float INVT = 1.f / 0.3f;
    int b = blockIdx.x, tid = threadIdx.x;
    int lane = tid & 63, wv = tid >> 6;
    __shared__ float s_logT[512], s_cs[512];
    __shared__ int s_x[512];
    __shared__ float s_csw[4][512];
    __shared__ float s_acc[16][112];
    __shared__ float s_pool[112], s_h2[100], s_fin[4];
    for (int l = tid; l < 512; l += 256) {
        s_logT[l] = logits[b * 512 + l] * INVT;
        s_x[l] = xidx[b * 512 + l];
    }
    __syncthreads();
    // wave-local softmax per k
    const int nk = (wv < 2) ? 3 : 2;
    float csl[8];
#pragma unroll
    for (int i = 0; i < 8; ++i) csl[i] = 0.f;
    float lt[8];
#pragma unroll
    for (int i = 0; i < 8; ++i) lt[i] = s_logT[lane * 8 + i];
    for (int j = 0; j < nk; ++j) {
        int k = wv + 4 * j;
        f32x4 u0 = *(const f32x4*)&u[(b * 10 + k) * 512 + lane * 8];
        f32x4 u1 = *(const f32x4*)&u[(b * 10 + k) * 512 + lane * 8 + 4];
        float nz[8];
#pragma unroll
        for (int i = 0; i < 8; ++i) {
            float vv = (i < 4) ? u0[i] : u1[i - 4];
            vv = fminf(fmaxf(vv, EPSV), 1.f - EPSV);
            nz[i] = -__logf(-__logf(vv)) * INVT + lt[i];
        }
        float m = nz[0];
#pragma unroll
        for (int i = 1; i < 8; ++i) m = fmaxf(m, nz[i]);
#pragma unroll
        for (int off = 1; off <= 32; off <<= 1) m = fmaxf(m, __shfl_xor(m, off, 64));
        float e[8], s = 0.f;
#pragma unroll
        for (int i = 0; i < 8; ++i) { e[i] = __expf(nz[i] - m); s += e[i]; }
#pragma unroll
        for (int off = 1; off <= 32; off <<= 1) s += __shfl_xor(s, off, 64);
        float inv = 1.f / s;
#pragma unroll
        for (int i = 0; i < 8; ++i) csl[i] = fmaxf(csl[i], e[i] * inv);
    }
#pragma unroll
    for (int i = 0; i < 8; ++i) s_csw[wv][lane * 8 + i] = csl[i];
    __syncthreads();
    for (int l = tid; l < 512; l += 256) {
        float c = fmaxf(fmaxf(s_csw[0][l], s_csw[1][l]),
                        fmaxf(s_csw[2][l], s_csw[3][l]));
        s_cs[l] = c;
        cs_out[b * 512 + l] = c;
    }
    __syncthreads();
    // pooled partial sums: thread (jg, c8) covers l = jg+16t, channels c8*8..+7
    int jg = tid >> 4, c8 = tid & 15;
    if (c8 < 14) {
        f32x4 pa = {0.f, 0.f, 0.f, 0.f}, pb = {0.f, 0.f, 0.f, 0.f};
#pragma unroll 4
        for (int l = jg; l < 512; l += 16) {
            int row = s_x[l];
            float cv = s_cs[l];
            short8 e8 = *(const short8*)&embT[(size_t)row * 112 + c8 * 8];
#pragma unroll
            for (int r = 0; r < 4; ++r) {
                pa[r] += cv * bfu(e8[r]);
                pb[r] += cv * bfu(e8[4 + r]);
            }
        }
        *(f32x4*)&s_acc[jg][c8 * 8] = pa;
        *(f32x4*)&s_acc[jg][c8 * 8 + 4] = pb;
    }
    __syncthreads();
    if (tid < 112) {
        float p = 0.f;
#pragma unroll
        for (int g = 0; g < 16; ++g) p += s_acc[g][tid];
        s_pool[tid] = p * (1.f / 512.f);
    }
    __syncthreads();
    if (tid < 100) {
        float a = f1b[tid];
        for (int i = 0; i < 100; ++i) a += s_pool[i] * f1w[tid * 100 + i];
        s_h2[tid] = fmaxf(a, 0.f);
    }
    __syncthreads();
    float v = (tid < 100) ? s_h2[tid] * hw[tid] : 0.f;
#pragma unroll
    for (int off = 32; off >= 1; off >>= 1) v += __shfl_xor(v, off, 64);
    if (lane == 0) s_fin[wv] = v;
    __syncthreads();
    if (tid == 0) {
        float z = s_fin[0] + s_fin[1] + s_fin[2] + s_fin[3] + hb[0];
        out[b] = 1.f / (1.f + __expf(-z));
    }
}

// ---------------------------------------------------------------------------
extern "C" void kernel_launch(void* const* d_in, const int* in_sizes, int n_in,
                              void* d_out, int out_size, void* d_ws, size_t ws_size,
                              hipStream_t stream) {
    const int*   x   = (const int*)d_in[0];
    const float* u   = (const float*)d_in[1];
    const float* emb = (const float*)d_in[2];
    const float* c1w = (const float*)d_in[3];
    const float* c1b = (const float*)d_in[4];
    const float* giw = (const float*)d_in[5];
    const float* gib = (const float*)d_in[6];
    const float* c2w = (const float*)d_in[7];
    const float* c2b = (const float*)d_in[8];
    const float* liw = (const float*)d_in[9];
    const float* lib = (const float*)d_in[10];
    const float* c3w = (const float*)d_in[11];
    const float* c3b = (const float*)d_in[12];
    const float* c4w = (const float*)d_in[13];
    const float* c4b = (const float*)d_in[14];
    const float* f1w = (const float*)d_in[15];
    const float* f1b = (const float*)d_in[16];
    const float* hww = (const float*)d_in[17];
    const float* hbb = (const float*)d_in[18];
    float* out = (float*)d_out;

    char* ws = (char*)d_ws;
    short* locT   = (short*)(ws + 0);           // [512][512][112] bf16 (58.7 MB)
    short* embT   = (short*)(ws + 58720256);    // [100000][112] bf16 (22.4 MB)
    short* A1     = (short*)(ws + 81120256);    // 10*448*16 B each
    short* A2     = (short*)(ws + 81191936);
    short* A3     = (short*)(ws + 81263616);
    short* A4     = (short*)(ws + 81335296);    // 4*448*16 B
    float* zg     = (float*)(ws + 81363968);    // [512][112]
    float* logits = (float*)(ws + 81593344);    // [512][512]
    float* hpart  = (float*)(ws + 82641920);    // [512][8][2][112]

    emb_cvt_kernel<<<12500, 256, 0, stream>>>(emb, embT);
    pack_all_kernel<<<238, 64, 0, stream>>>(c1w, c2w, liw, c3w, A1, A2, A3, A4);

    size_t smemA = 2 * 72 * SSTR * 2;             // 39168 B -> 4 blocks/CU
    fused_conv_kernel<<<dim3(8, 512), 256, smemA, stream>>>(
        x, embT, A1, A2, A3, c1b, c2b, lib, locT, hpart);
    pool_gate_kernel<<<512, 128, 0, stream>>>(hpart, giw, gib, c3w, c3b, zg);
    size_t smemB = 128 * SSTR * 2 + 2 * 128 * 4;  // 35840 B -> 4 blocks/CU
    conv3_logits_kernel<<<dim3(4, 512), 256, smemB, stream>>>(
        locT, A4, zg, c4w, c4b, logits);
    samp_head_kernel<<<512, 256, 0, stream>>>(
        u, logits, x, embT, f1w, f1b, hww, hbb, out + 512, out);
}